// Round 14
// baseline (595.207 us; speedup 1.0000x reference)
//
#include <hip/hip_runtime.h>
#include <hip/hip_bf16.h>

#define L_TOK 3645
#define MP    3712
#define DIMV  3456
#define EDIM  1024

typedef __attribute__((ext_vector_type(8))) short bf8;   // 8 bf16 in 4 VGPRs
typedef __attribute__((ext_vector_type(4))) short s4v;   // 4 bf16
typedef __attribute__((ext_vector_type(4))) float f4;    // MFMA accumulator

__device__ __forceinline__ short f2b(float f) {          // fp32 -> bf16 RNE
  union { float f; unsigned u; } v; v.f = f;
  unsigned r = v.u + 0x7fffu + ((v.u >> 16) & 1u);
  return (short)(r >> 16);
}
__device__ __forceinline__ float b2f(short s) {
  union { unsigned u; float f; } v; v.u = ((unsigned)(unsigned short)s) << 16;
  return v.f;
}
__device__ __forceinline__ void gld16(const void* g, void* l) {
  __builtin_amdgcn_global_load_lds(
      (const __attribute__((address_space(1))) void*)(unsigned long long)g,
      (__attribute__((address_space(3))) void*)(unsigned)(unsigned long long)l,
      16, 0, 0);
}

// ------- merged conversion kernel: 8 segments, flat 1-D grid ----------------
struct CvtArgs {
  const float *s0, *s1, *s2, *s3, *s4, *s5, *s6, *s7;
  short *d0, *d1, *d2, *d3, *d4, *d5, *d6, *d7;
};
#define SB0 3207168
#define SB1 4091904
#define SB2 4976640
#define SB3 5861376
#define SB4 6123520
#define SB5 6385664
#define SB6 6647808
#define SB7 7532544
__global__ __launch_bounds__(256) void k_cvtall(CvtArgs a) {
  int i = blockIdx.x * 256 + threadIdx.x;
  if (i >= SB7) return;
  const float* src; short* dst; int j;
  if (i < SB0) {
    j = i; src = a.s0; dst = a.d0;
    s4v o; o[0] = 0; o[1] = 0; o[2] = 0; o[3] = 0;
    if (j < 3149280) {
      float4 v = ((const float4*)src)[j];
      o[0] = f2b(v.x); o[1] = f2b(v.y); o[2] = f2b(v.z); o[3] = f2b(v.w);
    }
    ((s4v*)dst)[j] = o;
    return;
  }
  else if (i < SB1) { j = i - SB0; src = a.s1; dst = a.d1; }
  else if (i < SB2) { j = i - SB1; src = a.s2; dst = a.d2; }
  else if (i < SB3) { j = i - SB2; src = a.s3; dst = a.d3; }
  else if (i < SB4) { j = i - SB3; src = a.s4; dst = a.d4; }
  else if (i < SB5) { j = i - SB4; src = a.s5; dst = a.d5; }
  else if (i < SB6) { j = i - SB5; src = a.s6; dst = a.d6; }
  else              { j = i - SB6; src = a.s7; dst = a.d7; }
  float4 v = ((const float4*)src)[j];
  s4v o; o[0] = f2b(v.x); o[1] = f2b(v.y); o[2] = f2b(v.z); o[3] = f2b(v.w);
  ((s4v*)dst)[j] = o;
}

// wpb cvt with LN-gamma folded in: dst[n][k] = f2b(Wp[n][k] * g_{n>>10}[k])
__global__ __launch_bounds__(256)
void k_cvtwp(const float* __restrict__ src, short* __restrict__ dst,
             const float* __restrict__ g0, const float* __restrict__ g1,
             const float* __restrict__ g2) {
  int i = blockIdx.x * 256 + threadIdx.x;    // 786432 4-groups
  if (i >= 786432) return;
  int flat = i * 4;
  int k = flat & 1023;
  int z = flat >> 20;
  const float* g = (z == 0) ? g0 : (z == 1 ? g1 : g2);
  float4 v = ((const float4*)src)[i];
  float4 gv = *(const float4*)&g[k];
  s4v o; o[0] = f2b(v.x * gv.x); o[1] = f2b(v.y * gv.y);
  o[2] = f2b(v.z * gv.z); o[3] = f2b(v.w * gv.w);
  ((s4v*)dst)[i] = o;
}

// fp32 [n][n] -> bf16 transposed: dst[i][j] = src[j][i]
__global__ __launch_bounds__(256)
void k_cvt_t(const float* __restrict__ src, short* __restrict__ dst, int n) {
  __shared__ float T[64][65];
  const int bi = blockIdx.x * 64, bj = blockIdx.y * 64;
  const int tx = threadIdx.x & 63, ty = threadIdx.x >> 6;
#pragma unroll
  for (int r = 0; r < 64; r += 4)
    T[r + ty][tx] = src[(long)(bj + r + ty) * n + bi + tx];
  __syncthreads();
#pragma unroll
  for (int r = 0; r < 64; r += 4)
    dst[(long)(bi + r + ty) * n + bj + tx] = f2b(T[tx][r + ty]);
}

// bp[n] = sum_k opb[k] * Wt[n][k]
__global__ __launch_bounds__(256)
void k_bvec(const float* __restrict__ wt, const float* __restrict__ opb,
            float* __restrict__ bp) {
  const int n = blockIdx.x * 4 + (threadIdx.x >> 6);
  const int lane = threadIdx.x & 63;
  const float* row = wt + (long)n * 1024;
  float s = 0.f;
  for (int k = lane * 4; k < 1024; k += 256) {
    float4 w = *(const float4*)&row[k];
    float4 b = *(const float4*)&opb[k];
    s += w.x * b.x + w.y * b.y + w.z * b.z + w.w * b.w;
  }
#pragma unroll
  for (int off = 1; off < 64; off <<= 1) s += __shfl_xor(s, off);
  if (lane == 0) bp[n] = s;
}

// c1[z][n] = sum_k g_z[k]*Wp_z[n][k];  cb2[z][n] = sum_k lnb_z[k]*Wp_z[n][k] + ipb
__global__ __launch_bounds__(256)
void k_cvec(const float* __restrict__ wp,
            const float* g0, const float* g1, const float* g2,
            const float* b0, const float* b1, const float* b2,
            const float* __restrict__ ipb,
            float* __restrict__ c1, float* __restrict__ cb2) {
  const int z = blockIdx.y;
  const int n = blockIdx.x * 4 + (threadIdx.x >> 6);
  const int lane = threadIdx.x & 63;
  const float* g  = (z == 0) ? g0 : (z == 1 ? g1 : g2);
  const float* lb = (z == 0) ? b0 : (z == 1 ? b1 : b2);
  const float* row = wp + ((long)z * 1024 + n) * 1024;
  float s1 = 0.f, s2 = 0.f;
  for (int k = lane * 4; k < 1024; k += 256) {
    float4 w = *(const float4*)&row[k];
    float4 gv = *(const float4*)&g[k];
    float4 bv = *(const float4*)&lb[k];
    s1 += w.x * gv.x + w.y * gv.y + w.z * gv.z + w.w * gv.w;
    s2 += w.x * bv.x + w.y * bv.y + w.z * bv.z + w.w * bv.w;
  }
#pragma unroll
  for (int off = 1; off < 64; off <<= 1) {
    s1 += __shfl_xor(s1, off); s2 += __shfl_xor(s2, off);
  }
  if (lane == 0) { c1[z * 1024 + n] = s1; cb2[z * 1024 + n] = s2 + ipb[z * 1024 + n]; }
}

// per-row LN stats of aln: st[z*MP+row] = {mean, rstd}
__global__ __launch_bounds__(256)
void k_stats(const short* __restrict__ aln, float2* __restrict__ st) {
  const int z = blockIdx.y;
  const int row = blockIdx.x * 4 + (threadIdx.x >> 6);
  const int lane = threadIdx.x & 63;
  const short* a = aln + ((long)z * MP + row) * EDIM;
  float s = 0.f, q = 0.f;
  for (int k = lane * 4; k < 1024; k += 256) {
    s4v v = *(const s4v*)&a[k];
#pragma unroll
    for (int e = 0; e < 4; ++e) { float f = b2f(v[e]); s += f; q += f * f; }
  }
#pragma unroll
  for (int off = 1; off < 64; off <<= 1) {
    s += __shfl_xor(s, off); q += __shfl_xor(q, off);
  }
  if (lane == 0) {
    float m = s * (1.f / 1024.f);
    float var = q * (1.f / 1024.f) - m * m;
    float2 o; o.x = m; o.y = rsqrtf(var + 1e-5f);
    st[(long)z * MP + row] = o;
  }
}

#define GM_GELU   0
#define GM_BIAS   1
#define GM_QSCALE 2
#define GM_RESID  3
#define GM_PLAIN  4

// ---------------- 128x128 GEMM (proven r5 kernel) ----------------------------
template<int MODE>
__global__ __launch_bounds__(256)
void k_gemm(const short* __restrict__ A, long sA,
            const short* __restrict__ B, long sB,
            const float* __restrict__ bias0, const float* __restrict__ bias1,
            const float* __restrict__ bias2,
            void* __restrict__ Cout, long sC,
            int N, int K, const float* __restrict__ resid)
{
  __shared__ short As[2][128 * 32];
  __shared__ short Bs[2][128 * 32];
  const int tid  = threadIdx.x;
  const int z    = blockIdx.z;
  const int nwg  = gridDim.x * gridDim.y;
  const int orig = blockIdx.y * gridDim.x + blockIdx.x;
  const int qq   = nwg >> 3, rr = nwg & 7;
  const int xcd  = orig & 7, ofs = orig >> 3;
  const int swz  = (xcd < rr ? xcd * (qq + 1) : rr * (qq + 1) + (xcd - rr) * qq) + ofs;
  const int brow = (swz / gridDim.x) * 128;
  const int bcol = (swz % gridDim.x) * 128;

  const short* Ab = A + (long)z * sA;
  const short* Bb = B + (long)z * sB;
  const float* bias = (z == 0) ? bias0 : (z == 1 ? bias1 : bias2);

  const int wave = tid >> 6, lane = tid & 63;
  const int lg = lane >> 4, lc = lane & 15;
  const int m0 = (wave >> 1) * 64, n0 = (wave & 1) * 64;

  const int r0 = tid >> 2, seg = tid & 3;
  const int r1 = r0 + 64;
  const int so0 = (seg ^ ((r0 >> 1) & 3)) * 8;
  const int so1 = (seg ^ ((r1 >> 1) & 3)) * 8;
  const short* pA0 = Ab + (long)(brow + r0) * K + so0;
  const short* pA1 = Ab + (long)(brow + r1) * K + so1;
  const short* pB0 = Bb + (long)(bcol + r0) * K + so0;
  const short* pB1 = Bb + (long)(bcol + r1) * K + so1;

  f4 acc[4][4];
  f4 zero = {0.f, 0.f, 0.f, 0.f};
#pragma unroll
  for (int i = 0; i < 4; ++i)
#pragma unroll
    for (int j = 0; j < 4; ++j) acc[i][j] = zero;

  auto STAGE = [&](int buf) {
    gld16(pA0, &As[buf][tid * 8]);
    gld16(pA1, &As[buf][(tid + 256) * 8]);
    gld16(pB0, &Bs[buf][tid * 8]);
    gld16(pB1, &Bs[buf][(tid + 256) * 8]);
    pA0 += 32; pA1 += 32; pB0 += 32; pB1 += 32;
  };

  const int NT = K >> 5;
  STAGE(0);
  for (int t = 0; t < NT; ++t) {
    const int buf = t & 1;
    asm volatile("s_waitcnt vmcnt(0)" ::: "memory");
    __builtin_amdgcn_sched_barrier(0);
    __builtin_amdgcn_s_barrier();
    if (t + 1 < NT) STAGE((t + 1) & 1);
    const short* Al = &As[buf][0];
    const short* Bl = &Bs[buf][0];
    bf8 af[4], bfr[4];
#pragma unroll
    for (int mi = 0; mi < 4; ++mi) {
      int r = m0 + mi * 16 + lc;
      af[mi] = *(const bf8*)&Al[r * 32 + ((lg ^ ((r >> 1) & 3)) * 8)];
    }
#pragma unroll
    for (int ni = 0; ni < 4; ++ni) {
      int r = n0 + ni * 16 + lc;
      bfr[ni] = *(const bf8*)&Bl[r * 32 + ((lg ^ ((r >> 1) & 3)) * 8)];
    }
    __builtin_amdgcn_s_setprio(1);
#pragma unroll
    for (int mi = 0; mi < 4; ++mi)
#pragma unroll
      for (int ni = 0; ni < 4; ++ni)
        acc[mi][ni] = __builtin_amdgcn_mfma_f32_16x16x32_bf16(af[mi], bfr[ni], acc[mi][ni], 0, 0, 0);
    __builtin_amdgcn_s_setprio(0);
    __builtin_amdgcn_sched_barrier(0);
  }

  if (MODE == GM_RESID) {
    float* C = (float*)Cout;
#pragma unroll
    for (int ni = 0; ni < 4; ++ni) {
      int col = bcol + n0 + ni * 16 + lc;
      float bv = bias[col];
#pragma unroll
      for (int mi = 0; mi < 4; ++mi)
#pragma unroll
        for (int r = 0; r < 4; ++r) {
          int row = brow + m0 + mi * 16 + lg * 4 + r;
          if (row < L_TOK)
            C[(long)row * N + col] = acc[mi][ni][r] + bv + resid[(long)row * N + col];
        }
    }
  } else {
    short* C = (short*)Cout + (long)z * sC;
    const float alpha = (MODE == GM_QSCALE && z == 0) ? 0.08838834764831845f : 1.0f;
#pragma unroll
    for (int ni = 0; ni < 4; ++ni) {
      int col = bcol + n0 + ni * 16 + lc;
      float bv = 0.f;
      if (MODE != GM_PLAIN) bv = bias[col];
#pragma unroll
      for (int mi = 0; mi < 4; ++mi)
#pragma unroll
        for (int r = 0; r < 4; ++r) {
          int row = brow + m0 + mi * 16 + lg * 4 + r;
          float v = acc[mi][ni][r] + bv;
          if (MODE == GM_GELU) v = 0.5f * v * (1.f + erff(v * 0.70710678118654752f));
          v *= alpha;
          C[(long)row * EDIM + col] = f2b(v);
        }
    }
  }
}

// --------- in_proj with fused LayerNorm (reads raw aln + row stats) ----------
__global__ __launch_bounds__(256)
void k_gemmln(const short* __restrict__ A, long sA,
              const short* __restrict__ B, long sB,
              const float2* __restrict__ st,
              const float* __restrict__ c1, const float* __restrict__ cb2,
              short* __restrict__ Cout, long sC)
{
  __shared__ short As[2][128 * 32];
  __shared__ short Bs[2][128 * 32];
  const int tid  = threadIdx.x;
  const int z    = blockIdx.z;
  const int K    = EDIM;
  const int nwg  = gridDim.x * gridDim.y;
  const int orig = blockIdx.y * gridDim.x + blockIdx.x;
  const int qq   = nwg >> 3, rr = nwg & 7;
  const int xcd  = orig & 7, ofs = orig >> 3;
  const int swz  = (xcd < rr ? xcd * (qq + 1) : rr * (qq + 1) + (xcd - rr) * qq) + ofs;
  const int brow = (swz / gridDim.x) * 128;
  const int bcol = (swz % gridDim.x) * 128;

  const short* Ab = A + (long)z * sA;
  const short* Bb = B + (long)z * sB;

  const int wave = tid >> 6, lane = tid & 63;
  const int lg = lane >> 4, lc = lane & 15;
  const int m0 = (wave >> 1) * 64, n0 = (wave & 1) * 64;

  const int r0 = tid >> 2, seg = tid & 3;
  const int r1 = r0 + 64;
  const int so0 = (seg ^ ((r0 >> 1) & 3)) * 8;
  const int so1 = (seg ^ ((r1 >> 1) & 3)) * 8;
  const short* pA0 = Ab + (long)(brow + r0) * K + so0;
  const short* pA1 = Ab + (long)(brow + r1) * K + so1;
  const short* pB0 = Bb + (long)(bcol + r0) * K + so0;
  const short* pB1 = Bb + (long)(bcol + r1) * K + so1;

  f4 acc[4][4];
  f4 zero = {0.f, 0.f, 0.f, 0.f};
#pragma unroll
  for (int i = 0; i < 4; ++i)
#pragma unroll
    for (int j = 0; j < 4; ++j) acc[i][j] = zero;

  auto STAGE = [&](int buf) {
    gld16(pA0, &As[buf][tid * 8]);
    gld16(pA1, &As[buf][(tid + 256) * 8]);
    gld16(pB0, &Bs[buf][tid * 8]);
    gld16(pB1, &Bs[buf][(tid + 256) * 8]);
    pA0 += 32; pA1 += 32; pB0 += 32; pB1 += 32;
  };

  const int NT = K >> 5;
  STAGE(0);
  for (int t = 0; t < NT; ++t) {
    const int buf = t & 1;
    asm volatile("s_waitcnt vmcnt(0)" ::: "memory");
    __builtin_amdgcn_sched_barrier(0);
    __builtin_amdgcn_s_barrier();
    if (t + 1 < NT) STAGE((t + 1) & 1);
    const short* Al = &As[buf][0];
    const short* Bl = &Bs[buf][0];
    bf8 af[4], bfr[4];
#pragma unroll
    for (int mi = 0; mi < 4; ++mi) {
      int r = m0 + mi * 16 + lc;
      af[mi] = *(const bf8*)&Al[r * 32 + ((lg ^ ((r >> 1) & 3)) * 8)];
    }
#pragma unroll
    for (int ni = 0; ni < 4; ++ni) {
      int r = n0 + ni * 16 + lc;
      bfr[ni] = *(const bf8*)&Bl[r * 32 + ((lg ^ ((r >> 1) & 3)) * 8)];
    }
    __builtin_amdgcn_s_setprio(1);
#pragma unroll
    for (int mi = 0; mi < 4; ++mi)
#pragma unroll
      for (int ni = 0; ni < 4; ++ni)
        acc[mi][ni] = __builtin_amdgcn_mfma_f32_16x16x32_bf16(af[mi], bfr[ni], acc[mi][ni], 0, 0, 0);
    __builtin_amdgcn_s_setprio(0);
    __builtin_amdgcn_sched_barrier(0);
  }

  short* C = Cout + (long)z * sC;
  const float alpha = (z == 0) ? 0.08838834764831845f : 1.0f;
  float2 sv[4][4];
#pragma unroll
  for (int mi = 0; mi < 4; ++mi)
#pragma unroll
    for (int r = 0; r < 4; ++r)
      sv[mi][r] = st[(long)z * MP + brow + m0 + mi * 16 + lg * 4 + r];
#pragma unroll
  for (int ni = 0; ni < 4; ++ni) {
    int col = bcol + n0 + ni * 16 + lc;
    float c1v = c1[z * 1024 + col];
    float cbv = cb2[z * 1024 + col];
#pragma unroll
    for (int mi = 0; mi < 4; ++mi)
#pragma unroll
      for (int r = 0; r < 4; ++r) {
        int row = brow + m0 + mi * 16 + lg * 4 + r;
        float v = sv[mi][r].y * (acc[mi][ni][r] - sv[mi][r].x * c1v) + cbv;
        C[(long)row * EDIM + col] = f2b(v * alpha);
      }
  }
}

// ---------------- V transpose per head: vpT[h][d][kv] ----------------
__global__ __launch_bounds__(256)
void k_vtrans(const short* __restrict__ vp, short* __restrict__ vpT)
{
  const int kb = blockIdx.x * 64, h = blockIdx.y;
  __shared__ short T[64 * 128];
  const int tid = threadIdx.x;
#pragma unroll
  for (int i = 0; i < 4; ++i) {
    int c = tid + 256 * i;
    int r = c >> 4, x = c & 15;
    bf8 val = *(const bf8*)&vp[(long)(kb + r) * EDIM + h * 128 + x * 8];
    *(bf8*)&T[r * 128 + ((x ^ (r & 7)) * 8)] = val;
  }
  __syncthreads();
#pragma unroll
  for (int i = 0; i < 4; ++i) {
    int c = tid + 256 * i;
    int dr = c >> 3, x = c & 7;
    short tmp[8];
#pragma unroll
    for (int e = 0; e < 8; ++e) {
      int kv = x * 8 + e;
      tmp[e] = T[kv * 128 + (((dr >> 3) ^ (kv & 7)) << 3) + (dr & 7)];
    }
    *(bf8*)&vpT[((long)h * 128 + dr) * MP + kb + x * 8] = *(bf8*)tmp;
  }
}

// ------- fused attention, KV-split 4-way, reg-staged single-buffer K/V ------
// 48KB LDS -> 3 blocks/CU; grid 928 -> ~3.6 blocks/CU. Per tile: barrier(A,
// prev reads done) -> vmcnt(0) (regs landed, ~1 tile of slack) -> ds_write ->
// issue next loads -> lgkmcnt(0)+barrier(B) -> compute.
__global__ __launch_bounds__(256, 3)
void k_attn(const short* __restrict__ qp, const short* __restrict__ kp,
            const short* __restrict__ vpT,
            short* __restrict__ op0, short* __restrict__ op1,
            short* __restrict__ op2, short* __restrict__ op3,
            float* __restrict__ lsums)
{
  const int bx = blockIdx.x;
  const int h = bx & 7;
  const int t2 = bx >> 3;                 // 0..115
  const int qi = t2 % 29, sp = t2 / 29;   // sp in 0..3
  const int qb = qi * 128;
  short* opart = (sp == 0) ? op0 : (sp == 1) ? op1 : (sp == 2) ? op2 : op3;
  const int t0 = (sp == 0) ? 0  : (sp == 1) ? 15 : (sp == 2) ? 29 : 43;
  const int t1 = (sp == 0) ? 15 : (sp == 1) ? 29 : (sp == 2) ? 43 : 57;

  const int tid = threadIdx.x, wave = tid >> 6, lane = tid & 63;
  const int lg = lane >> 4, lc = lane & 15;
  __shared__ short Ks[64 * 128];   // 16KB, single-buffered
  __shared__ short Vs[128 * 64];   // 16KB
  __shared__ short Ps[4][32 * 64]; // 16KB

  const int q0 = qb + wave * 32;
  bf8 qf[2][4];
#pragma unroll
  for (int g = 0; g < 2; ++g)
#pragma unroll
    for (int d4 = 0; d4 < 4; ++d4)
      qf[g][d4] = *(const bf8*)&qp[(long)(q0 + g * 16 + lc) * EDIM + h * 128 + d4 * 32 + lg * 8];

  f4 oacc[2][8];
  f4 zero = {0.f, 0.f, 0.f, 0.f};
#pragma unroll
  for (int g = 0; g < 2; ++g)
#pragma unroll
    for (int dt = 0; dt < 8; ++dt) oacc[g][dt] = zero;
  float lsum0 = 0.f, lsum1 = 0.f;

  bf8 rK[4], rV[4];
  auto LOADREG = [&](int kb) {
#pragma unroll
    for (int i = 0; i < 4; ++i) {
      int c = tid + 256 * i; int r = c >> 4, x = c & 15;
      rK[i] = *(const bf8*)&kp[(long)(kb + r) * EDIM + h * 128 + (x ^ (r & 7)) * 8];
    }
#pragma unroll
    for (int i = 0; i < 4; ++i) {
      int c = tid + 256 * i; int dr = c >> 3, x = c & 7;
      rV[i] = *(const bf8*)&vpT[((long)h * 128 + dr) * MP + kb + (x ^ (dr & 7)) * 8];
    }
  };

  LOADREG(t0 * 64);

  for (int t = t0; t < t1; ++t) {
    const int kb = t * 64;
    __builtin_amdgcn_s_barrier();                      // (A) prev-tile reads done
    asm volatile("s_waitcnt vmcnt(0)" ::: "memory");   // tile-t regs landed
    __builtin_amdgcn_sched_barrier(0);
#pragma unroll
    for (int i = 0; i < 4; ++i) *(bf8*)&Ks[(tid + 256 * i) * 8] = rK[i];
#pragma unroll
    for (int i = 0; i < 4; ++i) *(bf8*)&Vs[(tid + 256 * i) * 8] = rV[i];
    if (t + 1 < t1) LOADREG(kb + 64);                  // issue next (vmcnt only)
    asm volatile("s_waitcnt lgkmcnt(0)" ::: "memory"); // my LDS writes committed
    __builtin_amdgcn_sched_barrier(0);
    __builtin_amdgcn_s_barrier();                      // (B) tile t visible
    __builtin_amdgcn_sched_barrier(0);

#pragma unroll
    for (int s = 0; s < 4; ++s) {
      const int krow = s * 16 + lc;
      bf8 kf[4];
#pragma unroll
      for (int d4 = 0; d4 < 4; ++d4)
        kf[d4] = *(const bf8*)&Ks[krow * 128 + (((d4 * 4 + lg) ^ (krow & 7)) * 8)];
      f4 sa0 = zero, sa1 = zero;
      __builtin_amdgcn_s_setprio(1);
#pragma unroll
      for (int d4 = 0; d4 < 4; ++d4) {
        sa0 = __builtin_amdgcn_mfma_f32_16x16x32_bf16(kf[d4], qf[0][d4], sa0, 0, 0, 0);
        sa1 = __builtin_amdgcn_mfma_f32_16x16x32_bf16(kf[d4], qf[1][d4], sa1, 0, 0, 0);
      }
      __builtin_amdgcn_s_setprio(0);
      const int kvb = kb + s * 16 + lg * 4;
#pragma unroll
      for (int g = 0; g < 2; ++g) {
        f4 sa = g ? sa1 : sa0;
        float p[4];
#pragma unroll
        for (int r = 0; r < 4; ++r) {
          float e = __expf(sa[r]);
          p[r] = (kvb + r < L_TOK) ? e : 0.f;
          if (g) lsum1 += p[r]; else lsum0 += p[r];
        }
        s4v pk; pk[0] = f2b(p[0]); pk[1] = f2b(p[1]); pk[2] = f2b(p[2]); pk[3] = f2b(p[3]);
        *(s4v*)&Ps[wave][(g * 16 + lc) * 64 + ((s * 16 + lg * 4) ^ ((lc & 7) << 3))] = pk;
      }
    }
    bf8 pf[2][2];
#pragma unroll
    for (int g = 0; g < 2; ++g) {
      pf[g][0] = *(const bf8*)&Ps[wave][(g * 16 + lc) * 64 + ((lg * 8) ^ ((lc & 7) << 3))];
      pf[g][1] = *(const bf8*)&Ps[wave][(g * 16 + lc) * 64 + ((32 + lg * 8) ^ ((lc & 7) << 3))];
    }
#pragma unroll
    for (int dt = 0; dt < 8; ++dt) {
      const int vrow = dt * 16 + lc;
      bf8 vf0 = *(const bf8*)&Vs[vrow * 64 + ((lg ^ (vrow & 7)) * 8)];
      bf8 vf1 = *(const bf8*)&Vs[vrow * 64 + (((4 + lg) ^ (vrow & 7)) * 8)];
      __builtin_amdgcn_s_setprio(1);
      oacc[0][dt] = __builtin_amdgcn_mfma_f32_16x16x32_bf16(pf[0][0], vf0, oacc[0][dt], 0, 0, 0);
      oacc[0][dt] = __builtin_amdgcn_mfma_f32_16x16x32_bf16(pf[0][1], vf1, oacc[0][dt], 0, 0, 0);
      oacc[1][dt] = __builtin_amdgcn_mfma_f32_16x16x32_bf16(pf[1][0], vf0, oacc[1][dt], 0, 0, 0);
      oacc[1][dt] = __builtin_amdgcn_mfma_f32_16x16x32_bf16(pf[1][1], vf1, oacc[1][dt], 0, 0, 0);
      __builtin_amdgcn_s_setprio(0);
    }
    __builtin_amdgcn_sched_barrier(0);
  }

  lsum0 += __shfl_xor(lsum0, 16);
  lsum0 += __shfl_xor(lsum0, 32);
  lsum1 += __shfl_xor(lsum1, 16);
  lsum1 += __shfl_xor(lsum1, 32);
  if (lg == 0) {
    lsums[((sp * 8) + h) * MP + q0 + lc]      = lsum0;
    lsums[((sp * 8) + h) * MP + q0 + 16 + lc] = lsum1;
  }
#pragma unroll
  for (int g = 0; g < 2; ++g)
#pragma unroll
    for (int dt = 0; dt < 8; ++dt)
#pragma unroll
      for (int r = 0; r < 4; ++r) {
        int orow = q0 + g * 16 + lg * 4 + r;
        opart[(long)orow * EDIM + h * 128 + dt * 16 + lc] = f2b(oacc[g][dt][r]);
      }
}

// ---------------- combine partials: ob = (p0+p1+p2+p3)/(ls0+..+ls3) ---------
__global__ __launch_bounds__(256)
void k_comb(const short* __restrict__ p0, const short* __restrict__ p1,
            const short* __restrict__ p2, const short* __restrict__ p3,
            const float* __restrict__ ls, short* __restrict__ ob)
{
  int i = blockIdx.x * 256 + threadIdx.x;   // one 8-short group
  int q = i >> 7;
  int h = (i & 127) >> 4;
  float rinv = 1.f / (ls[h * MP + q] + ls[(8 + h) * MP + q] +
                      ls[(16 + h) * MP + q] + ls[(24 + h) * MP + q]);
  bf8 a = ((const bf8*)p0)[i];
  bf8 b = ((const bf8*)p1)[i];
  bf8 c = ((const bf8*)p2)[i];
  bf8 d = ((const bf8*)p3)[i];
  bf8 o;
#pragma unroll
  for (int j = 0; j < 8; ++j)
    o[j] = f2b((b2f(a[j]) + b2f(b[j]) + b2f(c[j]) + b2f(d[j])) * rinv);
  ((bf8*)ob)[i] = o;
}

// ---------------- launch ----------------
extern "C" void kernel_launch(void* const* d_in, const int* in_sizes, int n_in,
                              void* d_out, int out_size, void* d_ws, size_t ws_size,
                              hipStream_t stream)
{
  const float* x   = (const float*)d_in[0];
  const float* ipb = (const float*)d_in[20];
  const float* opb = (const float*)d_in[22];

  char* ws = (char*)d_ws;
  // regA [0, 25657344): xb -> aln -> {pt0, pt1, ob}
  // tail [23068672, 25657344): stats/bp/c1/cb2/lsums — written only AFTER
  // GEMM1 consumes xb (r11 lesson).
  short*  xb     = (short*)(ws + 0);
  short*  aln    = (short*)(ws + 0);
  short*  pt0    = (short*)(ws + 0);
  short*  pt1    = (short*)(ws + 7602176);
  short*  ob     = (short*)(ws + 15466496);    // ends 23,068,672
  float2* stats  = (float2*)(ws + 23068672);
  float*  bp     = (float*)(ws + 23330816);
  float*  c1     = (float*)(ws + 23461888);
  float*  cb2    = (float*)(ws + 23592960);
  float*  lsums  = (float*)(ws + 23605248);    // 475,136 B, ends 24,080,384
  short*  h1     = (short*)(ws + 25657344);
  short*  proj   = (short*)(ws + 25657344);
  short*  w1b    = (short*)(ws + 48463872);
  short*  wprime = w1b;                        // W' = first 7,077,888 B of w1b
  short*  pt2    = (short*)(ws + 55541760);    // dead w1b tail after GEMM1
  short*  pt3    = (short*)(ws + 63143936);    // spills into dead w2b (ok)
  short*  w2b    = (short*)(ws + 69697536);
  short*  wpb    = (short*)(ws + 75988992);
  short*  woT    = (short*)(ws + 82280448);
  short*  wtb    = (short*)(ws + 84377600);
  short*  vpT    = (short*)(ws + 91455488);

  // 1. merged conversions (x-pad, w1 x3, w2 x3, wt)
  CvtArgs ca;
  ca.s0 = x;                      ca.d0 = xb;
  ca.s1 = (const float*)d_in[1];  ca.d1 = w1b;
  ca.s2 = (const float*)d_in[7];  ca.d2 = w1b + 3538944;
  ca.s3 = (const float*)d_in[13]; ca.d3 = w1b + 7077888;
  ca.s4 = (const float*)d_in[3];  ca.d4 = w2b;
  ca.s5 = (const float*)d_in[9];  ca.d5 = w2b + 1048576;
  ca.s6 = (const float*)d_in[15]; ca.d6 = w2b + 2097152;
  ca.s7 = (const float*)d_in[23]; ca.d7 = wtb;
  k_cvtall<<<(SB7 + 255) / 256, 256, 0, stream>>>(ca);
  // 2. wpb with LN gamma folded
  k_cvtwp<<<3072, 256, 0, stream>>>((const float*)d_in[19], wpb,
      (const float*)d_in[5], (const float*)d_in[11], (const float*)d_in[17]);
  // 3. Wo^T
  dim3 gct(16, 16);
  k_cvt_t<<<gct, 256, 0, stream>>>((const float*)d_in[21], woT, 1024);

  dim3 g3(8, 29, 3);
  // 4. MLP first linear + GELU (consumes xb; w1b/regA tails dead after)
  k_gemm<GM_GELU><<<g3, 256, 0, stream>>>(xb, 0, w1b, 3538944,
      (const float*)d_in[2], (const float*)d_in[8], (const float*)d_in[14],
      h1, (long)MP * EDIM, EDIM, DIMV, nullptr);
  // 5. composite bias b' = opb @ Wt^T
  k_bvec<<<864, 256, 0, stream>>>((const float*)d_in[23], opb, bp);
  // 6. LN correction vectors c1, cb2
  dim3 gcv(256, 3);
  k_cvec<<<gcv, 256, 0, stream>>>((const float*)d_in[19],
      (const float*)d_in[5], (const float*)d_in[11], (const float*)d_in[17],
      (const float*)d_in[6], (const float*)d_in[12], (const float*)d_in[18],
      ipb, c1, cb2);
  // 7. W' = Wt @ Wo (into dead w1b slot head)
  dim3 gwp(8, 27, 1);
  k_gemm<GM_PLAIN><<<gwp, 256, 0, stream>>>(wtb, 0, woT, 0,
      nullptr, nullptr, nullptr, wprime, 0, EDIM, EDIM, nullptr);
  // 8. MLP second linear + bias (h1 -> aln)
  k_gemm<GM_BIAS><<<g3, 256, 0, stream>>>(h1, (long)MP * EDIM, w2b, 1048576,
      (const float*)d_in[4], (const float*)d_in[10], (const float*)d_in[16],
      aln, (long)MP * EDIM, EDIM, EDIM, nullptr);
  // 9. per-row LN stats
  dim3 gst(MP / 4, 3);
  k_stats<<<gst, 256, 0, stream>>>(aln, stats);
  // 10. in_proj with fused LN (+q scale), aln -> proj
  k_gemmln<<<g3, 256, 0, stream>>>(aln, (long)MP * EDIM, wpb, 1048576,
      stats, c1, cb2, proj, (long)MP * EDIM);
  // 11. V transpose per head
  dim3 gt(MP / 64, 8);
  k_vtrans<<<gt, 256, 0, stream>>>(proj + 2L * MP * EDIM, vpT);
  // 12. attention, KV-split 4-way, reg-staged single-buffer K/V
  k_attn<<<29 * 4 * 8, 256, 0, stream>>>(proj, proj + (long)MP * EDIM, vpT,
      pt0, pt1, pt2, pt3, lsums);
  // 13. combine partials
  k_comb<<<(MP * EDIM / 8) / 256, 256, 0, stream>>>(pt0, pt1, pt2, pt3, lsums, ob);
  // 14. composite (out_proj ∘ to_out): out = ob @ W'^T + b' + x (fp32 out)
  dim3 g5(27, 29, 1);
  k_gemm<GM_RESID><<<g5, 256, 0, stream>>>(ob, 0, wprime, 0,
      bp, bp, bp, d_out, 0, DIMV, EDIM, x);
}

// Round 15
// 410.377 us; speedup vs baseline: 1.4504x; 1.4504x over previous
//
#include <hip/hip_runtime.h>
#include <hip/hip_bf16.h>

#define L_TOK 3645
#define MP    3712
#define DIMV  3456
#define EDIM  1024

typedef __attribute__((ext_vector_type(8))) short bf8;   // 8 bf16 in 4 VGPRs
typedef __attribute__((ext_vector_type(4))) short s4v;   // 4 bf16
typedef __attribute__((ext_vector_type(4))) float f4;    // MFMA accumulator

__device__ __forceinline__ short f2b(float f) {          // fp32 -> bf16 RNE
  union { float f; unsigned u; } v; v.f = f;
  unsigned r = v.u + 0x7fffu + ((v.u >> 16) & 1u);
  return (short)(r >> 16);
}
__device__ __forceinline__ float b2f(short s) {
  union { unsigned u; float f; } v; v.u = ((unsigned)(unsigned short)s) << 16;
  return v.f;
}
__device__ __forceinline__ void gld16(const void* g, void* l) {
  __builtin_amdgcn_global_load_lds(
      (const __attribute__((address_space(1))) void*)(unsigned long long)g,
      (__attribute__((address_space(3))) void*)(unsigned)(unsigned long long)l,
      16, 0, 0);
}

// ------- merged conversion kernel: 8 segments, flat 1-D grid ----------------
struct CvtArgs {
  const float *s0, *s1, *s2, *s3, *s4, *s5, *s6, *s7;
  short *d0, *d1, *d2, *d3, *d4, *d5, *d6, *d7;
};
#define SB0 3207168
#define SB1 4091904
#define SB2 4976640
#define SB3 5861376
#define SB4 6123520
#define SB5 6385664
#define SB6 6647808
#define SB7 7532544
__global__ __launch_bounds__(256) void k_cvtall(CvtArgs a) {
  int i = blockIdx.x * 256 + threadIdx.x;
  if (i >= SB7) return;
  const float* src; short* dst; int j;
  if (i < SB0) {
    j = i; src = a.s0; dst = a.d0;
    s4v o; o[0] = 0; o[1] = 0; o[2] = 0; o[3] = 0;
    if (j < 3149280) {
      float4 v = ((const float4*)src)[j];
      o[0] = f2b(v.x); o[1] = f2b(v.y); o[2] = f2b(v.z); o[3] = f2b(v.w);
    }
    ((s4v*)dst)[j] = o;
    return;
  }
  else if (i < SB1) { j = i - SB0; src = a.s1; dst = a.d1; }
  else if (i < SB2) { j = i - SB1; src = a.s2; dst = a.d2; }
  else if (i < SB3) { j = i - SB2; src = a.s3; dst = a.d3; }
  else if (i < SB4) { j = i - SB3; src = a.s4; dst = a.d4; }
  else if (i < SB5) { j = i - SB4; src = a.s5; dst = a.d5; }
  else if (i < SB6) { j = i - SB5; src = a.s6; dst = a.d6; }
  else              { j = i - SB6; src = a.s7; dst = a.d7; }
  float4 v = ((const float4*)src)[j];
  s4v o; o[0] = f2b(v.x); o[1] = f2b(v.y); o[2] = f2b(v.z); o[3] = f2b(v.w);
  ((s4v*)dst)[j] = o;
}

// wpb cvt with LN-gamma folded in: dst[n][k] = f2b(Wp[n][k] * g_{n>>10}[k])
__global__ __launch_bounds__(256)
void k_cvtwp(const float* __restrict__ src, short* __restrict__ dst,
             const float* __restrict__ g0, const float* __restrict__ g1,
             const float* __restrict__ g2) {
  int i = blockIdx.x * 256 + threadIdx.x;    // 786432 4-groups
  if (i >= 786432) return;
  int flat = i * 4;
  int k = flat & 1023;
  int z = flat >> 20;
  const float* g = (z == 0) ? g0 : (z == 1 ? g1 : g2);
  float4 v = ((const float4*)src)[i];
  float4 gv = *(const float4*)&g[k];
  s4v o; o[0] = f2b(v.x * gv.x); o[1] = f2b(v.y * gv.y);
  o[2] = f2b(v.z * gv.z); o[3] = f2b(v.w * gv.w);
  ((s4v*)dst)[i] = o;
}

// fp32 [n][n] -> bf16 transposed: dst[i][j] = src[j][i]
__global__ __launch_bounds__(256)
void k_cvt_t(const float* __restrict__ src, short* __restrict__ dst, int n) {
  __shared__ float T[64][65];
  const int bi = blockIdx.x * 64, bj = blockIdx.y * 64;
  const int tx = threadIdx.x & 63, ty = threadIdx.x >> 6;
#pragma unroll
  for (int r = 0; r < 64; r += 4)
    T[r + ty][tx] = src[(long)(bj + r + ty) * n + bi + tx];
  __syncthreads();
#pragma unroll
  for (int r = 0; r < 64; r += 4)
    dst[(long)(bi + r + ty) * n + bj + tx] = f2b(T[tx][r + ty]);
}

// bp[n] = sum_k opb[k] * Wt[n][k]
__global__ __launch_bounds__(256)
void k_bvec(const float* __restrict__ wt, const float* __restrict__ opb,
            float* __restrict__ bp) {
  const int n = blockIdx.x * 4 + (threadIdx.x >> 6);
  const int lane = threadIdx.x & 63;
  const float* row = wt + (long)n * 1024;
  float s = 0.f;
  for (int k = lane * 4; k < 1024; k += 256) {
    float4 w = *(const float4*)&row[k];
    float4 b = *(const float4*)&opb[k];
    s += w.x * b.x + w.y * b.y + w.z * b.z + w.w * b.w;
  }
#pragma unroll
  for (int off = 1; off < 64; off <<= 1) s += __shfl_xor(s, off);
  if (lane == 0) bp[n] = s;
}

// c1[z][n] = sum_k g_z[k]*Wp_z[n][k];  cb2[z][n] = sum_k lnb_z[k]*Wp_z[n][k] + ipb
__global__ __launch_bounds__(256)
void k_cvec(const float* __restrict__ wp,
            const float* g0, const float* g1, const float* g2,
            const float* b0, const float* b1, const float* b2,
            const float* __restrict__ ipb,
            float* __restrict__ c1, float* __restrict__ cb2) {
  const int z = blockIdx.y;
  const int n = blockIdx.x * 4 + (threadIdx.x >> 6);
  const int lane = threadIdx.x & 63;
  const float* g  = (z == 0) ? g0 : (z == 1 ? g1 : g2);
  const float* lb = (z == 0) ? b0 : (z == 1 ? b1 : b2);
  const float* row = wp + ((long)z * 1024 + n) * 1024;
  float s1 = 0.f, s2 = 0.f;
  for (int k = lane * 4; k < 1024; k += 256) {
    float4 w = *(const float4*)&row[k];
    float4 gv = *(const float4*)&g[k];
    float4 bv = *(const float4*)&lb[k];
    s1 += w.x * gv.x + w.y * gv.y + w.z * gv.z + w.w * gv.w;
    s2 += w.x * bv.x + w.y * bv.y + w.z * bv.z + w.w * bv.w;
  }
#pragma unroll
  for (int off = 1; off < 64; off <<= 1) {
    s1 += __shfl_xor(s1, off); s2 += __shfl_xor(s2, off);
  }
  if (lane == 0) { c1[z * 1024 + n] = s1; cb2[z * 1024 + n] = s2 + ipb[z * 1024 + n]; }
}

// per-row LN stats of aln: st[z*MP+row] = {mean, rstd}
__global__ __launch_bounds__(256)
void k_stats(const short* __restrict__ aln, float2* __restrict__ st) {
  const int z = blockIdx.y;
  const int row = blockIdx.x * 4 + (threadIdx.x >> 6);
  const int lane = threadIdx.x & 63;
  const short* a = aln + ((long)z * MP + row) * EDIM;
  float s = 0.f, q = 0.f;
  for (int k = lane * 4; k < 1024; k += 256) {
    s4v v = *(const s4v*)&a[k];
#pragma unroll
    for (int e = 0; e < 4; ++e) { float f = b2f(v[e]); s += f; q += f * f; }
  }
#pragma unroll
  for (int off = 1; off < 64; off <<= 1) {
    s += __shfl_xor(s, off); q += __shfl_xor(q, off);
  }
  if (lane == 0) {
    float m = s * (1.f / 1024.f);
    float var = q * (1.f / 1024.f) - m * m;
    float2 o; o.x = m; o.y = rsqrtf(var + 1e-5f);
    st[(long)z * MP + row] = o;
  }
}

#define GM_GELU   0
#define GM_BIAS   1
#define GM_QSCALE 2
#define GM_RESID  3
#define GM_PLAIN  4

// ---------------- 128x128 GEMM (proven r5 kernel) ----------------------------
template<int MODE>
__global__ __launch_bounds__(256)
void k_gemm(const short* __restrict__ A, long sA,
            const short* __restrict__ B, long sB,
            const float* __restrict__ bias0, const float* __restrict__ bias1,
            const float* __restrict__ bias2,
            void* __restrict__ Cout, long sC,
            int N, int K, const float* __restrict__ resid)
{
  __shared__ short As[2][128 * 32];
  __shared__ short Bs[2][128 * 32];
  const int tid  = threadIdx.x;
  const int z    = blockIdx.z;
  const int nwg  = gridDim.x * gridDim.y;
  const int orig = blockIdx.y * gridDim.x + blockIdx.x;
  const int qq   = nwg >> 3, rr = nwg & 7;
  const int xcd  = orig & 7, ofs = orig >> 3;
  const int swz  = (xcd < rr ? xcd * (qq + 1) : rr * (qq + 1) + (xcd - rr) * qq) + ofs;
  const int brow = (swz / gridDim.x) * 128;
  const int bcol = (swz % gridDim.x) * 128;

  const short* Ab = A + (long)z * sA;
  const short* Bb = B + (long)z * sB;
  const float* bias = (z == 0) ? bias0 : (z == 1 ? bias1 : bias2);

  const int wave = tid >> 6, lane = tid & 63;
  const int lg = lane >> 4, lc = lane & 15;
  const int m0 = (wave >> 1) * 64, n0 = (wave & 1) * 64;

  const int r0 = tid >> 2, seg = tid & 3;
  const int r1 = r0 + 64;
  const int so0 = (seg ^ ((r0 >> 1) & 3)) * 8;
  const int so1 = (seg ^ ((r1 >> 1) & 3)) * 8;
  const short* pA0 = Ab + (long)(brow + r0) * K + so0;
  const short* pA1 = Ab + (long)(brow + r1) * K + so1;
  const short* pB0 = Bb + (long)(bcol + r0) * K + so0;
  const short* pB1 = Bb + (long)(bcol + r1) * K + so1;

  f4 acc[4][4];
  f4 zero = {0.f, 0.f, 0.f, 0.f};
#pragma unroll
  for (int i = 0; i < 4; ++i)
#pragma unroll
    for (int j = 0; j < 4; ++j) acc[i][j] = zero;

  auto STAGE = [&](int buf) {
    gld16(pA0, &As[buf][tid * 8]);
    gld16(pA1, &As[buf][(tid + 256) * 8]);
    gld16(pB0, &Bs[buf][tid * 8]);
    gld16(pB1, &Bs[buf][(tid + 256) * 8]);
    pA0 += 32; pA1 += 32; pB0 += 32; pB1 += 32;
  };

  const int NT = K >> 5;
  STAGE(0);
  for (int t = 0; t < NT; ++t) {
    const int buf = t & 1;
    asm volatile("s_waitcnt vmcnt(0)" ::: "memory");
    __builtin_amdgcn_sched_barrier(0);
    __builtin_amdgcn_s_barrier();
    if (t + 1 < NT) STAGE((t + 1) & 1);
    const short* Al = &As[buf][0];
    const short* Bl = &Bs[buf][0];
    bf8 af[4], bfr[4];
#pragma unroll
    for (int mi = 0; mi < 4; ++mi) {
      int r = m0 + mi * 16 + lc;
      af[mi] = *(const bf8*)&Al[r * 32 + ((lg ^ ((r >> 1) & 3)) * 8)];
    }
#pragma unroll
    for (int ni = 0; ni < 4; ++ni) {
      int r = n0 + ni * 16 + lc;
      bfr[ni] = *(const bf8*)&Bl[r * 32 + ((lg ^ ((r >> 1) & 3)) * 8)];
    }
    __builtin_amdgcn_s_setprio(1);
#pragma unroll
    for (int mi = 0; mi < 4; ++mi)
#pragma unroll
      for (int ni = 0; ni < 4; ++ni)
        acc[mi][ni] = __builtin_amdgcn_mfma_f32_16x16x32_bf16(af[mi], bfr[ni], acc[mi][ni], 0, 0, 0);
    __builtin_amdgcn_s_setprio(0);
    __builtin_amdgcn_sched_barrier(0);
  }

  if (MODE == GM_RESID) {
    float* C = (float*)Cout;
#pragma unroll
    for (int ni = 0; ni < 4; ++ni) {
      int col = bcol + n0 + ni * 16 + lc;
      float bv = bias[col];
#pragma unroll
      for (int mi = 0; mi < 4; ++mi)
#pragma unroll
        for (int r = 0; r < 4; ++r) {
          int row = brow + m0 + mi * 16 + lg * 4 + r;
          if (row < L_TOK)
            C[(long)row * N + col] = acc[mi][ni][r] + bv + resid[(long)row * N + col];
        }
    }
  } else {
    short* C = (short*)Cout + (long)z * sC;
    const float alpha = (MODE == GM_QSCALE && z == 0) ? 0.08838834764831845f : 1.0f;
#pragma unroll
    for (int ni = 0; ni < 4; ++ni) {
      int col = bcol + n0 + ni * 16 + lc;
      float bv = 0.f;
      if (MODE != GM_PLAIN) bv = bias[col];
#pragma unroll
      for (int mi = 0; mi < 4; ++mi)
#pragma unroll
        for (int r = 0; r < 4; ++r) {
          int row = brow + m0 + mi * 16 + lg * 4 + r;
          float v = acc[mi][ni][r] + bv;
          if (MODE == GM_GELU) v = 0.5f * v * (1.f + erff(v * 0.70710678118654752f));
          v *= alpha;
          C[(long)row * EDIM + col] = f2b(v);
        }
    }
  }
}

// --------- in_proj with fused LayerNorm (reads raw aln + row stats) ----------
__global__ __launch_bounds__(256)
void k_gemmln(const short* __restrict__ A, long sA,
              const short* __restrict__ B, long sB,
              const float2* __restrict__ st,
              const float* __restrict__ c1, const float* __restrict__ cb2,
              short* __restrict__ Cout, long sC)
{
  __shared__ short As[2][128 * 32];
  __shared__ short Bs[2][128 * 32];
  const int tid  = threadIdx.x;
  const int z    = blockIdx.z;
  const int K    = EDIM;
  const int nwg  = gridDim.x * gridDim.y;
  const int orig = blockIdx.y * gridDim.x + blockIdx.x;
  const int qq   = nwg >> 3, rr = nwg & 7;
  const int xcd  = orig & 7, ofs = orig >> 3;
  const int swz  = (xcd < rr ? xcd * (qq + 1) : rr * (qq + 1) + (xcd - rr) * qq) + ofs;
  const int brow = (swz / gridDim.x) * 128;
  const int bcol = (swz % gridDim.x) * 128;

  const short* Ab = A + (long)z * sA;
  const short* Bb = B + (long)z * sB;

  const int wave = tid >> 6, lane = tid & 63;
  const int lg = lane >> 4, lc = lane & 15;
  const int m0 = (wave >> 1) * 64, n0 = (wave & 1) * 64;

  const int r0 = tid >> 2, seg = tid & 3;
  const int r1 = r0 + 64;
  const int so0 = (seg ^ ((r0 >> 1) & 3)) * 8;
  const int so1 = (seg ^ ((r1 >> 1) & 3)) * 8;
  const short* pA0 = Ab + (long)(brow + r0) * K + so0;
  const short* pA1 = Ab + (long)(brow + r1) * K + so1;
  const short* pB0 = Bb + (long)(bcol + r0) * K + so0;
  const short* pB1 = Bb + (long)(bcol + r1) * K + so1;

  f4 acc[4][4];
  f4 zero = {0.f, 0.f, 0.f, 0.f};
#pragma unroll
  for (int i = 0; i < 4; ++i)
#pragma unroll
    for (int j = 0; j < 4; ++j) acc[i][j] = zero;

  auto STAGE = [&](int buf) {
    gld16(pA0, &As[buf][tid * 8]);
    gld16(pA1, &As[buf][(tid + 256) * 8]);
    gld16(pB0, &Bs[buf][tid * 8]);
    gld16(pB1, &Bs[buf][(tid + 256) * 8]);
    pA0 += 32; pA1 += 32; pB0 += 32; pB1 += 32;
  };

  const int NT = K >> 5;
  STAGE(0);
  for (int t = 0; t < NT; ++t) {
    const int buf = t & 1;
    asm volatile("s_waitcnt vmcnt(0)" ::: "memory");
    __builtin_amdgcn_sched_barrier(0);
    __builtin_amdgcn_s_barrier();
    if (t + 1 < NT) STAGE((t + 1) & 1);
    const short* Al = &As[buf][0];
    const short* Bl = &Bs[buf][0];
    bf8 af[4], bfr[4];
#pragma unroll
    for (int mi = 0; mi < 4; ++mi) {
      int r = m0 + mi * 16 + lc;
      af[mi] = *(const bf8*)&Al[r * 32 + ((lg ^ ((r >> 1) & 3)) * 8)];
    }
#pragma unroll
    for (int ni = 0; ni < 4; ++ni) {
      int r = n0 + ni * 16 + lc;
      bfr[ni] = *(const bf8*)&Bl[r * 32 + ((lg ^ ((r >> 1) & 3)) * 8)];
    }
    __builtin_amdgcn_s_setprio(1);
#pragma unroll
    for (int mi = 0; mi < 4; ++mi)
#pragma unroll
      for (int ni = 0; ni < 4; ++ni)
        acc[mi][ni] = __builtin_amdgcn_mfma_f32_16x16x32_bf16(af[mi], bfr[ni], acc[mi][ni], 0, 0, 0);
    __builtin_amdgcn_s_setprio(0);
    __builtin_amdgcn_sched_barrier(0);
  }

  short* C = Cout + (long)z * sC;
  const float alpha = (z == 0) ? 0.08838834764831845f : 1.0f;
  float2 sv[4][4];
#pragma unroll
  for (int mi = 0; mi < 4; ++mi)
#pragma unroll
    for (int r = 0; r < 4; ++r)
      sv[mi][r] = st[(long)z * MP + brow + m0 + mi * 16 + lg * 4 + r];
#pragma unroll
  for (int ni = 0; ni < 4; ++ni) {
    int col = bcol + n0 + ni * 16 + lc;
    float c1v = c1[z * 1024 + col];
    float cbv = cb2[z * 1024 + col];
#pragma unroll
    for (int mi = 0; mi < 4; ++mi)
#pragma unroll
      for (int r = 0; r < 4; ++r) {
        int row = brow + m0 + mi * 16 + lg * 4 + r;
        float v = sv[mi][r].y * (acc[mi][ni][r] - sv[mi][r].x * c1v) + cbv;
        C[(long)row * EDIM + col] = f2b(v * alpha);
      }
  }
}

// ---------------- V transpose per head: vpT[h][d][kv] ----------------
__global__ __launch_bounds__(256)
void k_vtrans(const short* __restrict__ vp, short* __restrict__ vpT)
{
  const int kb = blockIdx.x * 64, h = blockIdx.y;
  __shared__ short T[64 * 128];
  const int tid = threadIdx.x;
#pragma unroll
  for (int i = 0; i < 4; ++i) {
    int c = tid + 256 * i;
    int r = c >> 4, x = c & 15;
    bf8 val = *(const bf8*)&vp[(long)(kb + r) * EDIM + h * 128 + x * 8];
    *(bf8*)&T[r * 128 + ((x ^ (r & 7)) * 8)] = val;
  }
  __syncthreads();
#pragma unroll
  for (int i = 0; i < 4; ++i) {
    int c = tid + 256 * i;
    int dr = c >> 3, x = c & 7;
    short tmp[8];
#pragma unroll
    for (int e = 0; e < 8; ++e) {
      int kv = x * 8 + e;
      tmp[e] = T[kv * 128 + (((dr >> 3) ^ (kv & 7)) << 3) + (dr & 7)];
    }
    *(bf8*)&vpT[((long)h * 128 + dr) * MP + kb + x * 8] = *(bf8*)tmp;
  }
}

// ---------------- fused attention, KV-split 2-way (flash-decoding) ----------
__global__ __launch_bounds__(256)
void k_attn(const short* __restrict__ qp, const short* __restrict__ kp,
            const short* __restrict__ vpT,
            short* __restrict__ op0, short* __restrict__ op1,
            float* __restrict__ lsums)
{
  const int bx = blockIdx.x;
  const int h = bx & 7;
  const int t2 = bx >> 3;                 // 0..57
  const int qi = t2 % 29, sp = t2 / 29;
  const int qb = qi * 128;
  short* opart = sp ? op1 : op0;
  const int t0 = sp ? 29 : 0, t1 = sp ? 57 : 29;

  const int tid = threadIdx.x, wave = tid >> 6, lane = tid & 63;
  const int lg = lane >> 4, lc = lane & 15;
  __shared__ short Ks[2][64 * 128];
  __shared__ short Vs[2][128 * 64];
  __shared__ short Ps[4][32 * 64];

  const int q0 = qb + wave * 32;
  bf8 qf[2][4];
#pragma unroll
  for (int g = 0; g < 2; ++g)
#pragma unroll
    for (int d4 = 0; d4 < 4; ++d4)
      qf[g][d4] = *(const bf8*)&qp[(long)(q0 + g * 16 + lc) * EDIM + h * 128 + d4 * 32 + lg * 8];

  f4 oacc[2][8];
  f4 zero = {0.f, 0.f, 0.f, 0.f};
#pragma unroll
  for (int g = 0; g < 2; ++g)
#pragma unroll
    for (int dt = 0; dt < 8; ++dt) oacc[g][dt] = zero;
  float lsum0 = 0.f, lsum1 = 0.f;

  auto STAGE = [&](short* ksb, short* vsb, int kb) {
#pragma unroll
    for (int i = 0; i < 4; ++i) {
      int c = tid + 256 * i; int r = c >> 4, x = c & 15;
      gld16(&kp[(long)(kb + r) * EDIM + h * 128 + (x ^ (r & 7)) * 8], &ksb[c * 8]);
    }
#pragma unroll
    for (int i = 0; i < 4; ++i) {
      int c = tid + 256 * i; int dr = c >> 3, x = c & 7;
      gld16(&vpT[((long)h * 128 + dr) * MP + kb + (x ^ (dr & 7)) * 8], &vsb[c * 8]);
    }
  };

  STAGE(Ks[t0 & 1], Vs[t0 & 1], t0 * 64);

  for (int t = t0; t < t1; ++t) {
    const int kb = t * 64;
    const short* ksb = Ks[t & 1];
    const short* vsb = Vs[t & 1];
    __builtin_amdgcn_s_barrier();
    if (t + 1 < t1) {
      STAGE(Ks[(t + 1) & 1], Vs[(t + 1) & 1], kb + 64);
      asm volatile("s_waitcnt vmcnt(8)" ::: "memory");
    } else {
      asm volatile("s_waitcnt vmcnt(0)" ::: "memory");
    }
    __builtin_amdgcn_sched_barrier(0);
    __builtin_amdgcn_s_barrier();
    __builtin_amdgcn_sched_barrier(0);

#pragma unroll
    for (int s = 0; s < 4; ++s) {
      const int krow = s * 16 + lc;
      bf8 kf[4];
#pragma unroll
      for (int d4 = 0; d4 < 4; ++d4)
        kf[d4] = *(const bf8*)&ksb[krow * 128 + (((d4 * 4 + lg) ^ (krow & 7)) * 8)];
      f4 sa0 = zero, sa1 = zero;
      __builtin_amdgcn_s_setprio(1);
#pragma unroll
      for (int d4 = 0; d4 < 4; ++d4) {
        sa0 = __builtin_amdgcn_mfma_f32_16x16x32_bf16(kf[d4], qf[0][d4], sa0, 0, 0, 0);
        sa1 = __builtin_amdgcn_mfma_f32_16x16x32_bf16(kf[d4], qf[1][d4], sa1, 0, 0, 0);
      }
      __builtin_amdgcn_s_setprio(0);
      const int kvb = kb + s * 16 + lg * 4;
#pragma unroll
      for (int g = 0; g < 2; ++g) {
        f4 sa = g ? sa1 : sa0;
        float p[4];
#pragma unroll
        for (int r = 0; r < 4; ++r) {
          float e = __expf(sa[r]);
          p[r] = (kvb + r < L_TOK) ? e : 0.f;
          if (g) lsum1 += p[r]; else lsum0 += p[r];
        }
        s4v pk; pk[0] = f2b(p[0]); pk[1] = f2b(p[1]); pk[2] = f2b(p[2]); pk[3] = f2b(p[3]);
        *(s4v*)&Ps[wave][(g * 16 + lc) * 64 + ((s * 16 + lg * 4) ^ ((lc & 7) << 3))] = pk;
      }
    }
    bf8 pf[2][2];
#pragma unroll
    for (int g = 0; g < 2; ++g) {
      pf[g][0] = *(const bf8*)&Ps[wave][(g * 16 + lc) * 64 + ((lg * 8) ^ ((lc & 7) << 3))];
      pf[g][1] = *(const bf8*)&Ps[wave][(g * 16 + lc) * 64 + ((32 + lg * 8) ^ ((lc & 7) << 3))];
    }
#pragma unroll
    for (int dt = 0; dt < 8; ++dt) {
      const int vrow = dt * 16 + lc;
      bf8 vf0 = *(const bf8*)&vsb[vrow * 64 + ((lg ^ (vrow & 7)) * 8)];
      bf8 vf1 = *(const bf8*)&vsb[vrow * 64 + (((4 + lg) ^ (vrow & 7)) * 8)];
      __builtin_amdgcn_s_setprio(1);
      oacc[0][dt] = __builtin_amdgcn_mfma_f32_16x16x32_bf16(pf[0][0], vf0, oacc[0][dt], 0, 0, 0);
      oacc[0][dt] = __builtin_amdgcn_mfma_f32_16x16x32_bf16(pf[0][1], vf1, oacc[0][dt], 0, 0, 0);
      oacc[1][dt] = __builtin_amdgcn_mfma_f32_16x16x32_bf16(pf[1][0], vf0, oacc[1][dt], 0, 0, 0);
      oacc[1][dt] = __builtin_amdgcn_mfma_f32_16x16x32_bf16(pf[1][1], vf1, oacc[1][dt], 0, 0, 0);
      __builtin_amdgcn_s_setprio(0);
    }
    __builtin_amdgcn_sched_barrier(0);
  }

  lsum0 += __shfl_xor(lsum0, 16);
  lsum0 += __shfl_xor(lsum0, 32);
  lsum1 += __shfl_xor(lsum1, 16);
  lsum1 += __shfl_xor(lsum1, 32);
  if (lg == 0) {
    lsums[((sp * 8) + h) * MP + q0 + lc]      = lsum0;
    lsums[((sp * 8) + h) * MP + q0 + 16 + lc] = lsum1;
  }
#pragma unroll
  for (int g = 0; g < 2; ++g)
#pragma unroll
    for (int dt = 0; dt < 8; ++dt)
#pragma unroll
      for (int r = 0; r < 4; ++r) {
        int orow = q0 + g * 16 + lg * 4 + r;
        opart[(long)orow * EDIM + h * 128 + dt * 16 + lc] = f2b(oacc[g][dt][r]);
      }
}

// ---------------- combine partials: ob = (p0+p1)/(ls0+ls1) ------------------
__global__ __launch_bounds__(256)
void k_comb(const short* __restrict__ p0, const short* __restrict__ p1,
            const float* __restrict__ ls, short* __restrict__ ob)
{
  int i = blockIdx.x * 256 + threadIdx.x;   // one 8-short group
  int q = i >> 7;
  int h = (i & 127) >> 4;
  float rinv = 1.f / (ls[h * MP + q] + ls[(8 + h) * MP + q]);
  bf8 a = ((const bf8*)p0)[i];
  bf8 b = ((const bf8*)p1)[i];
  bf8 o;
#pragma unroll
  for (int j = 0; j < 8; ++j) o[j] = f2b((b2f(a[j]) + b2f(b[j])) * rinv);
  ((bf8*)ob)[i] = o;
}

// ---------------- launch ----------------
extern "C" void kernel_launch(void* const* d_in, const int* in_sizes, int n_in,
                              void* d_out, int out_size, void* d_ws, size_t ws_size,
                              hipStream_t stream)
{
  const float* x   = (const float*)d_in[0];
  const float* ipb = (const float*)d_in[20];
  const float* opb = (const float*)d_in[22];

  char* ws = (char*)d_ws;
  // regA [0, 25657344): xb -> aln -> {pt0, pt1, lsums, ob}
  // tail [23068672, 25657344): stats/bp/c1/cb2 — written only AFTER GEMM1
  // consumes xb (r11 lesson).
  short*  xb     = (short*)(ws + 0);
  short*  aln    = (short*)(ws + 0);
  short*  pt0    = (short*)(ws + 0);
  short*  pt1    = (short*)(ws + 7602176);
  float*  lsums  = (float*)(ws + 15204352);
  short*  ob     = (short*)(ws + 15466496);
  float2* stats  = (float2*)(ws + 23068672);
  float*  bp     = (float*)(ws + 23330816);
  float*  c1     = (float*)(ws + 23461888);
  float*  cb2    = (float*)(ws + 23592960);
  short*  h1     = (short*)(ws + 25657344);
  short*  proj   = (short*)(ws + 25657344);
  short*  w1b    = (short*)(ws + 48463872);
  short*  wprime = w1b;
  short*  w2b    = (short*)(ws + 69697536);
  short*  wpb    = (short*)(ws + 75988992);
  short*  woT    = (short*)(ws + 82280448);
  short*  wtb    = (short*)(ws + 84377600);
  short*  vpT    = (short*)(ws + 91455488);

  // 1. merged conversions (x-pad, w1 x3, w2 x3, wt)
  CvtArgs ca;
  ca.s0 = x;                      ca.d0 = xb;
  ca.s1 = (const float*)d_in[1];  ca.d1 = w1b;
  ca.s2 = (const float*)d_in[7];  ca.d2 = w1b + 3538944;
  ca.s3 = (const float*)d_in[13]; ca.d3 = w1b + 7077888;
  ca.s4 = (const float*)d_in[3];  ca.d4 = w2b;
  ca.s5 = (const float*)d_in[9];  ca.d5 = w2b + 1048576;
  ca.s6 = (const float*)d_in[15]; ca.d6 = w2b + 2097152;
  ca.s7 = (const float*)d_in[23]; ca.d7 = wtb;
  k_cvtall<<<(SB7 + 255) / 256, 256, 0, stream>>>(ca);
  // 2. wpb with LN gamma folded
  k_cvtwp<<<3072, 256, 0, stream>>>((const float*)d_in[19], wpb,
      (const float*)d_in[5], (const float*)d_in[11], (const float*)d_in[17]);
  // 3. Wo^T
  dim3 gct(16, 16);
  k_cvt_t<<<gct, 256, 0, stream>>>((const float*)d_in[21], woT, 1024);

  dim3 g3(8, 29, 3);
  // 4. MLP first linear + GELU (consumes xb — regA tail becomes dead after this)
  k_gemm<GM_GELU><<<g3, 256, 0, stream>>>(xb, 0, w1b, 3538944,
      (const float*)d_in[2], (const float*)d_in[8], (const float*)d_in[14],
      h1, (long)MP * EDIM, EDIM, DIMV, nullptr);
  // 5. composite bias b' = opb @ Wt^T  (into now-dead xb tail)
  k_bvec<<<864, 256, 0, stream>>>((const float*)d_in[23], opb, bp);
  // 6. LN correction vectors c1, cb2 (into now-dead xb tail)
  dim3 gcv(256, 3);
  k_cvec<<<gcv, 256, 0, stream>>>((const float*)d_in[19],
      (const float*)d_in[5], (const float*)d_in[11], (const float*)d_in[17],
      (const float*)d_in[6], (const float*)d_in[12], (const float*)d_in[18],
      ipb, c1, cb2);
  // 7. W' = Wt @ Wo (into dead w1b slot)
  dim3 gwp(8, 27, 1);
  k_gemm<GM_PLAIN><<<gwp, 256, 0, stream>>>(wtb, 0, woT, 0,
      nullptr, nullptr, nullptr, wprime, 0, EDIM, EDIM, nullptr);
  // 8. MLP second linear + bias (h1 -> aln, overwrites dead xb)
  k_gemm<GM_BIAS><<<g3, 256, 0, stream>>>(h1, (long)MP * EDIM, w2b, 1048576,
      (const float*)d_in[4], (const float*)d_in[10], (const float*)d_in[16],
      aln, (long)MP * EDIM, EDIM, EDIM, nullptr);
  // 9. per-row LN stats
  dim3 gst(MP / 4, 3);
  k_stats<<<gst, 256, 0, stream>>>(aln, stats);
  // 10. in_proj with fused LN (+q scale), aln -> proj (overwrites dead h1)
  k_gemmln<<<g3, 256, 0, stream>>>(aln, (long)MP * EDIM, wpb, 1048576,
      stats, c1, cb2, proj, (long)MP * EDIM);
  // 11. V transpose per head
  dim3 gt(MP / 64, 8);
  k_vtrans<<<gt, 256, 0, stream>>>(proj + 2L * MP * EDIM, vpT);
  // 12. attention, KV-split 2-way (partials into dead regA)
  k_attn<<<29 * 2 * 8, 256, 0, stream>>>(proj, proj + (long)MP * EDIM, vpT,
      pt0, pt1, lsums);
  // 13. combine partials
  k_comb<<<(MP * EDIM / 8) / 256, 256, 0, stream>>>(pt0, pt1, lsums, ob);
  // 14. composite (out_proj ∘ to_out): out = ob @ W'^T + b' + x (fp32 out)
  dim3 g5(27, 29, 1);
  k_gemm<GM_RESID><<<g5, 256, 0, stream>>>(ob, 0, wprime, 0,
      bp, bp, bp, d_out, 0, DIMV, EDIM, x);
}

// Round 16
// 402.719 us; speedup vs baseline: 1.4780x; 1.0190x over previous
//
#include <hip/hip_runtime.h>
#include <hip/hip_bf16.h>

#define L_TOK 3645
#define MP    3712
#define DIMV  3456
#define EDIM  1024

typedef __attribute__((ext_vector_type(8))) short bf8;   // 8 bf16 in 4 VGPRs
typedef __attribute__((ext_vector_type(4))) short s4v;   // 4 bf16
typedef __attribute__((ext_vector_type(4))) float f4;    // MFMA accumulator

__device__ __forceinline__ short f2b(float f) {          // fp32 -> bf16 RNE
  union { float f; unsigned u; } v; v.f = f;
  unsigned r = v.u + 0x7fffu + ((v.u >> 16) & 1u);
  return (short)(r >> 16);
}
__device__ __forceinline__ float b2f(short s) {
  union { unsigned u; float f; } v; v.u = ((unsigned)(unsigned short)s) << 16;
  return v.f;
}
__device__ __forceinline__ void gld16(const void* g, void* l) {
  __builtin_amdgcn_global_load_lds(
      (const __attribute__((address_space(1))) void*)(unsigned long long)g,
      (__attribute__((address_space(3))) void*)(unsigned)(unsigned long long)l,
      16, 0, 0);
}

// ------- merged conversion kernel: 8 segments, flat 1-D grid ----------------
struct CvtArgs {
  const float *s0, *s1, *s2, *s3, *s4, *s5, *s6, *s7;
  short *d0, *d1, *d2, *d3, *d4, *d5, *d6, *d7;
};
#define SB0 3207168
#define SB1 4091904
#define SB2 4976640
#define SB3 5861376
#define SB4 6123520
#define SB5 6385664
#define SB6 6647808
#define SB7 7532544
__global__ __launch_bounds__(256) void k_cvtall(CvtArgs a) {
  int i = blockIdx.x * 256 + threadIdx.x;
  if (i >= SB7) return;
  const float* src; short* dst; int j;
  if (i < SB0) {
    j = i; src = a.s0; dst = a.d0;
    s4v o; o[0] = 0; o[1] = 0; o[2] = 0; o[3] = 0;
    if (j < 3149280) {
      float4 v = ((const float4*)src)[j];
      o[0] = f2b(v.x); o[1] = f2b(v.y); o[2] = f2b(v.z); o[3] = f2b(v.w);
    }
    ((s4v*)dst)[j] = o;
    return;
  }
  else if (i < SB1) { j = i - SB0; src = a.s1; dst = a.d1; }
  else if (i < SB2) { j = i - SB1; src = a.s2; dst = a.d2; }
  else if (i < SB3) { j = i - SB2; src = a.s3; dst = a.d3; }
  else if (i < SB4) { j = i - SB3; src = a.s4; dst = a.d4; }
  else if (i < SB5) { j = i - SB4; src = a.s5; dst = a.d5; }
  else if (i < SB6) { j = i - SB5; src = a.s6; dst = a.d6; }
  else              { j = i - SB6; src = a.s7; dst = a.d7; }
  float4 v = ((const float4*)src)[j];
  s4v o; o[0] = f2b(v.x); o[1] = f2b(v.y); o[2] = f2b(v.z); o[3] = f2b(v.w);
  ((s4v*)dst)[j] = o;
}

// wpb cvt with LN-gamma folded in: dst[n][k] = f2b(Wp[n][k] * g_{n>>10}[k])
__global__ __launch_bounds__(256)
void k_cvtwp(const float* __restrict__ src, short* __restrict__ dst,
             const float* __restrict__ g0, const float* __restrict__ g1,
             const float* __restrict__ g2) {
  int i = blockIdx.x * 256 + threadIdx.x;    // 786432 4-groups
  if (i >= 786432) return;
  int flat = i * 4;
  int k = flat & 1023;
  int z = flat >> 20;
  const float* g = (z == 0) ? g0 : (z == 1 ? g1 : g2);
  float4 v = ((const float4*)src)[i];
  float4 gv = *(const float4*)&g[k];
  s4v o; o[0] = f2b(v.x * gv.x); o[1] = f2b(v.y * gv.y);
  o[2] = f2b(v.z * gv.z); o[3] = f2b(v.w * gv.w);
  ((s4v*)dst)[i] = o;
}

// fp32 [n][n] -> bf16 transposed: dst[i][j] = src[j][i]
__global__ __launch_bounds__(256)
void k_cvt_t(const float* __restrict__ src, short* __restrict__ dst, int n) {
  __shared__ float T[64][65];
  const int bi = blockIdx.x * 64, bj = blockIdx.y * 64;
  const int tx = threadIdx.x & 63, ty = threadIdx.x >> 6;
#pragma unroll
  for (int r = 0; r < 64; r += 4)
    T[r + ty][tx] = src[(long)(bj + r + ty) * n + bi + tx];
  __syncthreads();
#pragma unroll
  for (int r = 0; r < 64; r += 4)
    dst[(long)(bi + r + ty) * n + bj + tx] = f2b(T[tx][r + ty]);
}

// bp[n] = sum_k opb[k] * Wt[n][k]
__global__ __launch_bounds__(256)
void k_bvec(const float* __restrict__ wt, const float* __restrict__ opb,
            float* __restrict__ bp) {
  const int n = blockIdx.x * 4 + (threadIdx.x >> 6);
  const int lane = threadIdx.x & 63;
  const float* row = wt + (long)n * 1024;
  float s = 0.f;
  for (int k = lane * 4; k < 1024; k += 256) {
    float4 w = *(const float4*)&row[k];
    float4 b = *(const float4*)&opb[k];
    s += w.x * b.x + w.y * b.y + w.z * b.z + w.w * b.w;
  }
#pragma unroll
  for (int off = 1; off < 64; off <<= 1) s += __shfl_xor(s, off);
  if (lane == 0) bp[n] = s;
}

// c1[z][n] = sum_k g_z[k]*Wp_z[n][k];  cb2[z][n] = sum_k lnb_z[k]*Wp_z[n][k] + ipb
__global__ __launch_bounds__(256)
void k_cvec(const float* __restrict__ wp,
            const float* g0, const float* g1, const float* g2,
            const float* b0, const float* b1, const float* b2,
            const float* __restrict__ ipb,
            float* __restrict__ c1, float* __restrict__ cb2) {
  const int z = blockIdx.y;
  const int n = blockIdx.x * 4 + (threadIdx.x >> 6);
  const int lane = threadIdx.x & 63;
  const float* g  = (z == 0) ? g0 : (z == 1 ? g1 : g2);
  const float* lb = (z == 0) ? b0 : (z == 1 ? b1 : b2);
  const float* row = wp + ((long)z * 1024 + n) * 1024;
  float s1 = 0.f, s2 = 0.f;
  for (int k = lane * 4; k < 1024; k += 256) {
    float4 w = *(const float4*)&row[k];
    float4 gv = *(const float4*)&g[k];
    float4 bv = *(const float4*)&lb[k];
    s1 += w.x * gv.x + w.y * gv.y + w.z * gv.z + w.w * gv.w;
    s2 += w.x * bv.x + w.y * bv.y + w.z * bv.z + w.w * bv.w;
  }
#pragma unroll
  for (int off = 1; off < 64; off <<= 1) {
    s1 += __shfl_xor(s1, off); s2 += __shfl_xor(s2, off);
  }
  if (lane == 0) { c1[z * 1024 + n] = s1; cb2[z * 1024 + n] = s2 + ipb[z * 1024 + n]; }
}

// per-row LN stats of aln: st[z*MP+row] = {mean, rstd}
__global__ __launch_bounds__(256)
void k_stats(const short* __restrict__ aln, float2* __restrict__ st) {
  const int z = blockIdx.y;
  const int row = blockIdx.x * 4 + (threadIdx.x >> 6);
  const int lane = threadIdx.x & 63;
  const short* a = aln + ((long)z * MP + row) * EDIM;
  float s = 0.f, q = 0.f;
  for (int k = lane * 4; k < 1024; k += 256) {
    s4v v = *(const s4v*)&a[k];
#pragma unroll
    for (int e = 0; e < 4; ++e) { float f = b2f(v[e]); s += f; q += f * f; }
  }
#pragma unroll
  for (int off = 1; off < 64; off <<= 1) {
    s += __shfl_xor(s, off); q += __shfl_xor(q, off);
  }
  if (lane == 0) {
    float m = s * (1.f / 1024.f);
    float var = q * (1.f / 1024.f) - m * m;
    float2 o; o.x = m; o.y = rsqrtf(var + 1e-5f);
    st[(long)z * MP + row] = o;
  }
}

#define GM_GELU   0
#define GM_BIAS   1
#define GM_QSCALE 2
#define GM_RESID  3
#define GM_PLAIN  4

// ---------------- 128x128 GEMM (proven r5 kernel) ----------------------------
template<int MODE>
__global__ __launch_bounds__(256)
void k_gemm(const short* __restrict__ A, long sA,
            const short* __restrict__ B, long sB,
            const float* __restrict__ bias0, const float* __restrict__ bias1,
            const float* __restrict__ bias2,
            void* __restrict__ Cout, long sC,
            int N, int K, const float* __restrict__ resid)
{
  __shared__ short As[2][128 * 32];
  __shared__ short Bs[2][128 * 32];
  const int tid  = threadIdx.x;
  const int z    = blockIdx.z;
  const int nwg  = gridDim.x * gridDim.y;
  const int orig = blockIdx.y * gridDim.x + blockIdx.x;
  const int qq   = nwg >> 3, rr = nwg & 7;
  const int xcd  = orig & 7, ofs = orig >> 3;
  const int swz  = (xcd < rr ? xcd * (qq + 1) : rr * (qq + 1) + (xcd - rr) * qq) + ofs;
  const int brow = (swz / gridDim.x) * 128;
  const int bcol = (swz % gridDim.x) * 128;

  const short* Ab = A + (long)z * sA;
  const short* Bb = B + (long)z * sB;
  const float* bias = (z == 0) ? bias0 : (z == 1 ? bias1 : bias2);

  const int wave = tid >> 6, lane = tid & 63;
  const int lg = lane >> 4, lc = lane & 15;
  const int m0 = (wave >> 1) * 64, n0 = (wave & 1) * 64;

  const int r0 = tid >> 2, seg = tid & 3;
  const int r1 = r0 + 64;
  const int so0 = (seg ^ ((r0 >> 1) & 3)) * 8;
  const int so1 = (seg ^ ((r1 >> 1) & 3)) * 8;
  const short* pA0 = Ab + (long)(brow + r0) * K + so0;
  const short* pA1 = Ab + (long)(brow + r1) * K + so1;
  const short* pB0 = Bb + (long)(bcol + r0) * K + so0;
  const short* pB1 = Bb + (long)(bcol + r1) * K + so1;

  f4 acc[4][4];
  f4 zero = {0.f, 0.f, 0.f, 0.f};
#pragma unroll
  for (int i = 0; i < 4; ++i)
#pragma unroll
    for (int j = 0; j < 4; ++j) acc[i][j] = zero;

  auto STAGE = [&](int buf) {
    gld16(pA0, &As[buf][tid * 8]);
    gld16(pA1, &As[buf][(tid + 256) * 8]);
    gld16(pB0, &Bs[buf][tid * 8]);
    gld16(pB1, &Bs[buf][(tid + 256) * 8]);
    pA0 += 32; pA1 += 32; pB0 += 32; pB1 += 32;
  };

  const int NT = K >> 5;
  STAGE(0);
  for (int t = 0; t < NT; ++t) {
    const int buf = t & 1;
    asm volatile("s_waitcnt vmcnt(0)" ::: "memory");
    __builtin_amdgcn_sched_barrier(0);
    __builtin_amdgcn_s_barrier();
    if (t + 1 < NT) STAGE((t + 1) & 1);
    const short* Al = &As[buf][0];
    const short* Bl = &Bs[buf][0];
    bf8 af[4], bfr[4];
#pragma unroll
    for (int mi = 0; mi < 4; ++mi) {
      int r = m0 + mi * 16 + lc;
      af[mi] = *(const bf8*)&Al[r * 32 + ((lg ^ ((r >> 1) & 3)) * 8)];
    }
#pragma unroll
    for (int ni = 0; ni < 4; ++ni) {
      int r = n0 + ni * 16 + lc;
      bfr[ni] = *(const bf8*)&Bl[r * 32 + ((lg ^ ((r >> 1) & 3)) * 8)];
    }
    __builtin_amdgcn_s_setprio(1);
#pragma unroll
    for (int mi = 0; mi < 4; ++mi)
#pragma unroll
      for (int ni = 0; ni < 4; ++ni)
        acc[mi][ni] = __builtin_amdgcn_mfma_f32_16x16x32_bf16(af[mi], bfr[ni], acc[mi][ni], 0, 0, 0);
    __builtin_amdgcn_s_setprio(0);
    __builtin_amdgcn_sched_barrier(0);
  }

  if (MODE == GM_RESID) {
    float* C = (float*)Cout;
#pragma unroll
    for (int ni = 0; ni < 4; ++ni) {
      int col = bcol + n0 + ni * 16 + lc;
      float bv = bias[col];
#pragma unroll
      for (int mi = 0; mi < 4; ++mi)
#pragma unroll
        for (int r = 0; r < 4; ++r) {
          int row = brow + m0 + mi * 16 + lg * 4 + r;
          if (row < L_TOK)
            C[(long)row * N + col] = acc[mi][ni][r] + bv + resid[(long)row * N + col];
        }
    }
  } else {
    short* C = (short*)Cout + (long)z * sC;
    const float alpha = (MODE == GM_QSCALE && z == 0) ? 0.08838834764831845f : 1.0f;
#pragma unroll
    for (int ni = 0; ni < 4; ++ni) {
      int col = bcol + n0 + ni * 16 + lc;
      float bv = 0.f;
      if (MODE != GM_PLAIN) bv = bias[col];
#pragma unroll
      for (int mi = 0; mi < 4; ++mi)
#pragma unroll
        for (int r = 0; r < 4; ++r) {
          int row = brow + m0 + mi * 16 + lg * 4 + r;
          float v = acc[mi][ni][r] + bv;
          if (MODE == GM_GELU) v = 0.5f * v * (1.f + erff(v * 0.70710678118654752f));
          v *= alpha;
          C[(long)row * EDIM + col] = f2b(v);
        }
    }
  }
}

// --------- in_proj with fused LayerNorm (reads raw aln + row stats) ----------
__global__ __launch_bounds__(256)
void k_gemmln(const short* __restrict__ A, long sA,
              const short* __restrict__ B, long sB,
              const float2* __restrict__ st,
              const float* __restrict__ c1, const float* __restrict__ cb2,
              short* __restrict__ Cout, long sC)
{
  __shared__ short As[2][128 * 32];
  __shared__ short Bs[2][128 * 32];
  const int tid  = threadIdx.x;
  const int z    = blockIdx.z;
  const int K    = EDIM;
  const int nwg  = gridDim.x * gridDim.y;
  const int orig = blockIdx.y * gridDim.x + blockIdx.x;
  const int qq   = nwg >> 3, rr = nwg & 7;
  const int xcd  = orig & 7, ofs = orig >> 3;
  const int swz  = (xcd < rr ? xcd * (qq + 1) : rr * (qq + 1) + (xcd - rr) * qq) + ofs;
  const int brow = (swz / gridDim.x) * 128;
  const int bcol = (swz % gridDim.x) * 128;

  const short* Ab = A + (long)z * sA;
  const short* Bb = B + (long)z * sB;

  const int wave = tid >> 6, lane = tid & 63;
  const int lg = lane >> 4, lc = lane & 15;
  const int m0 = (wave >> 1) * 64, n0 = (wave & 1) * 64;

  const int r0 = tid >> 2, seg = tid & 3;
  const int r1 = r0 + 64;
  const int so0 = (seg ^ ((r0 >> 1) & 3)) * 8;
  const int so1 = (seg ^ ((r1 >> 1) & 3)) * 8;
  const short* pA0 = Ab + (long)(brow + r0) * K + so0;
  const short* pA1 = Ab + (long)(brow + r1) * K + so1;
  const short* pB0 = Bb + (long)(bcol + r0) * K + so0;
  const short* pB1 = Bb + (long)(bcol + r1) * K + so1;

  f4 acc[4][4];
  f4 zero = {0.f, 0.f, 0.f, 0.f};
#pragma unroll
  for (int i = 0; i < 4; ++i)
#pragma unroll
    for (int j = 0; j < 4; ++j) acc[i][j] = zero;

  auto STAGE = [&](int buf) {
    gld16(pA0, &As[buf][tid * 8]);
    gld16(pA1, &As[buf][(tid + 256) * 8]);
    gld16(pB0, &Bs[buf][tid * 8]);
    gld16(pB1, &Bs[buf][(tid + 256) * 8]);
    pA0 += 32; pA1 += 32; pB0 += 32; pB1 += 32;
  };

  const int NT = K >> 5;
  STAGE(0);
  for (int t = 0; t < NT; ++t) {
    const int buf = t & 1;
    asm volatile("s_waitcnt vmcnt(0)" ::: "memory");
    __builtin_amdgcn_sched_barrier(0);
    __builtin_amdgcn_s_barrier();
    if (t + 1 < NT) STAGE((t + 1) & 1);
    const short* Al = &As[buf][0];
    const short* Bl = &Bs[buf][0];
    bf8 af[4], bfr[4];
#pragma unroll
    for (int mi = 0; mi < 4; ++mi) {
      int r = m0 + mi * 16 + lc;
      af[mi] = *(const bf8*)&Al[r * 32 + ((lg ^ ((r >> 1) & 3)) * 8)];
    }
#pragma unroll
    for (int ni = 0; ni < 4; ++ni) {
      int r = n0 + ni * 16 + lc;
      bfr[ni] = *(const bf8*)&Bl[r * 32 + ((lg ^ ((r >> 1) & 3)) * 8)];
    }
    __builtin_amdgcn_s_setprio(1);
#pragma unroll
    for (int mi = 0; mi < 4; ++mi)
#pragma unroll
      for (int ni = 0; ni < 4; ++ni)
        acc[mi][ni] = __builtin_amdgcn_mfma_f32_16x16x32_bf16(af[mi], bfr[ni], acc[mi][ni], 0, 0, 0);
    __builtin_amdgcn_s_setprio(0);
    __builtin_amdgcn_sched_barrier(0);
  }

  short* C = Cout + (long)z * sC;
  const float alpha = (z == 0) ? 0.08838834764831845f : 1.0f;
  float2 sv[4][4];
#pragma unroll
  for (int mi = 0; mi < 4; ++mi)
#pragma unroll
    for (int r = 0; r < 4; ++r)
      sv[mi][r] = st[(long)z * MP + brow + m0 + mi * 16 + lg * 4 + r];
#pragma unroll
  for (int ni = 0; ni < 4; ++ni) {
    int col = bcol + n0 + ni * 16 + lc;
    float c1v = c1[z * 1024 + col];
    float cbv = cb2[z * 1024 + col];
#pragma unroll
    for (int mi = 0; mi < 4; ++mi)
#pragma unroll
      for (int r = 0; r < 4; ++r) {
        int row = brow + m0 + mi * 16 + lg * 4 + r;
        float v = sv[mi][r].y * (acc[mi][ni][r] - sv[mi][r].x * c1v) + cbv;
        C[(long)row * EDIM + col] = f2b(v * alpha);
      }
  }
}

// ---------------- V transpose per head: vpT[h][d][kv] ----------------
__global__ __launch_bounds__(256)
void k_vtrans(const short* __restrict__ vp, short* __restrict__ vpT)
{
  const int kb = blockIdx.x * 64, h = blockIdx.y;
  __shared__ short T[64 * 128];
  const int tid = threadIdx.x;
#pragma unroll
  for (int i = 0; i < 4; ++i) {
    int c = tid + 256 * i;
    int r = c >> 4, x = c & 15;
    bf8 val = *(const bf8*)&vp[(long)(kb + r) * EDIM + h * 128 + x * 8];
    *(bf8*)&T[r * 128 + ((x ^ (r & 7)) * 8)] = val;
  }
  __syncthreads();
#pragma unroll
  for (int i = 0; i < 4; ++i) {
    int c = tid + 256 * i;
    int dr = c >> 3, x = c & 7;
    short tmp[8];
#pragma unroll
    for (int e = 0; e < 8; ++e) {
      int kv = x * 8 + e;
      tmp[e] = T[kv * 128 + (((dr >> 3) ^ (kv & 7)) << 3) + (dr & 7)];
    }
    *(bf8*)&vpT[((long)h * 128 + dr) * MP + kb + x * 8] = *(bf8*)tmp;
  }
}

// ------- fused attention, KV-split 4-way, single-buffered gld16 K/V ---------
// 48KB LDS -> 3 blocks/CU; grid 928 -> ~3.6 blocks/CU demand. Per tile:
// barrier (prev reads done) -> gld16 stage -> vmcnt(0) -> barrier -> compute.
// VGPR stays ~110 (no reg staging, no launch_bounds cap — r14 lesson).
__global__ __launch_bounds__(256)
void k_attn(const short* __restrict__ qp, const short* __restrict__ kp,
            const short* __restrict__ vpT,
            short* __restrict__ op0, short* __restrict__ op1,
            short* __restrict__ op2, short* __restrict__ op3,
            float* __restrict__ lsums)
{
  const int bx = blockIdx.x;
  const int h = bx & 7;
  const int t2 = bx >> 3;                 // 0..115
  const int qi = t2 % 29, sp = t2 / 29;   // sp in 0..3
  const int qb = qi * 128;
  short* opart = (sp == 0) ? op0 : (sp == 1) ? op1 : (sp == 2) ? op2 : op3;
  const int t0 = (sp == 0) ? 0  : (sp == 1) ? 15 : (sp == 2) ? 29 : 43;
  const int t1 = (sp == 0) ? 15 : (sp == 1) ? 29 : (sp == 2) ? 43 : 57;

  const int tid = threadIdx.x, wave = tid >> 6, lane = tid & 63;
  const int lg = lane >> 4, lc = lane & 15;
  __shared__ short Ks[64 * 128];   // 16KB, single-buffered
  __shared__ short Vs[128 * 64];   // 16KB
  __shared__ short Ps[4][32 * 64]; // 16KB

  const int q0 = qb + wave * 32;
  bf8 qf[2][4];
#pragma unroll
  for (int g = 0; g < 2; ++g)
#pragma unroll
    for (int d4 = 0; d4 < 4; ++d4)
      qf[g][d4] = *(const bf8*)&qp[(long)(q0 + g * 16 + lc) * EDIM + h * 128 + d4 * 32 + lg * 8];

  f4 oacc[2][8];
  f4 zero = {0.f, 0.f, 0.f, 0.f};
#pragma unroll
  for (int g = 0; g < 2; ++g)
#pragma unroll
    for (int dt = 0; dt < 8; ++dt) oacc[g][dt] = zero;
  float lsum0 = 0.f, lsum1 = 0.f;

  auto STAGE = [&](int kb) {
#pragma unroll
    for (int i = 0; i < 4; ++i) {
      int c = tid + 256 * i; int r = c >> 4, x = c & 15;
      gld16(&kp[(long)(kb + r) * EDIM + h * 128 + (x ^ (r & 7)) * 8], &Ks[c * 8]);
    }
#pragma unroll
    for (int i = 0; i < 4; ++i) {
      int c = tid + 256 * i; int dr = c >> 3, x = c & 7;
      gld16(&vpT[((long)h * 128 + dr) * MP + kb + (x ^ (dr & 7)) * 8], &Vs[c * 8]);
    }
  };

  for (int t = t0; t < t1; ++t) {
    const int kb = t * 64;
    __builtin_amdgcn_s_barrier();                      // prev-tile reads all done
    STAGE(kb);                                         // overwrite single buffer
    asm volatile("s_waitcnt vmcnt(0)" ::: "memory");   // my loads landed
    __builtin_amdgcn_sched_barrier(0);
    __builtin_amdgcn_s_barrier();                      // everyone's loads landed
    __builtin_amdgcn_sched_barrier(0);

#pragma unroll
    for (int s = 0; s < 4; ++s) {
      const int krow = s * 16 + lc;
      bf8 kf[4];
#pragma unroll
      for (int d4 = 0; d4 < 4; ++d4)
        kf[d4] = *(const bf8*)&Ks[krow * 128 + (((d4 * 4 + lg) ^ (krow & 7)) * 8)];
      f4 sa0 = zero, sa1 = zero;
      __builtin_amdgcn_s_setprio(1);
#pragma unroll
      for (int d4 = 0; d4 < 4; ++d4) {
        sa0 = __builtin_amdgcn_mfma_f32_16x16x32_bf16(kf[d4], qf[0][d4], sa0, 0, 0, 0);
        sa1 = __builtin_amdgcn_mfma_f32_16x16x32_bf16(kf[d4], qf[1][d4], sa1, 0, 0, 0);
      }
      __builtin_amdgcn_s_setprio(0);
      const int kvb = kb + s * 16 + lg * 4;
#pragma unroll
      for (int g = 0; g < 2; ++g) {
        f4 sa = g ? sa1 : sa0;
        float p[4];
#pragma unroll
        for (int r = 0; r < 4; ++r) {
          float e = __expf(sa[r]);
          p[r] = (kvb + r < L_TOK) ? e : 0.f;
          if (g) lsum1 += p[r]; else lsum0 += p[r];
        }
        s4v pk; pk[0] = f2b(p[0]); pk[1] = f2b(p[1]); pk[2] = f2b(p[2]); pk[3] = f2b(p[3]);
        *(s4v*)&Ps[wave][(g * 16 + lc) * 64 + ((s * 16 + lg * 4) ^ ((lc & 7) << 3))] = pk;
      }
    }
    bf8 pf[2][2];
#pragma unroll
    for (int g = 0; g < 2; ++g) {
      pf[g][0] = *(const bf8*)&Ps[wave][(g * 16 + lc) * 64 + ((lg * 8) ^ ((lc & 7) << 3))];
      pf[g][1] = *(const bf8*)&Ps[wave][(g * 16 + lc) * 64 + ((32 + lg * 8) ^ ((lc & 7) << 3))];
    }
#pragma unroll
    for (int dt = 0; dt < 8; ++dt) {
      const int vrow = dt * 16 + lc;
      bf8 vf0 = *(const bf8*)&Vs[vrow * 64 + ((lg ^ (vrow & 7)) * 8)];
      bf8 vf1 = *(const bf8*)&Vs[vrow * 64 + (((4 + lg) ^ (vrow & 7)) * 8)];
      __builtin_amdgcn_s_setprio(1);
      oacc[0][dt] = __builtin_amdgcn_mfma_f32_16x16x32_bf16(pf[0][0], vf0, oacc[0][dt], 0, 0, 0);
      oacc[0][dt] = __builtin_amdgcn_mfma_f32_16x16x32_bf16(pf[0][1], vf1, oacc[0][dt], 0, 0, 0);
      oacc[1][dt] = __builtin_amdgcn_mfma_f32_16x16x32_bf16(pf[1][0], vf0, oacc[1][dt], 0, 0, 0);
      oacc[1][dt] = __builtin_amdgcn_mfma_f32_16x16x32_bf16(pf[1][1], vf1, oacc[1][dt], 0, 0, 0);
      __builtin_amdgcn_s_setprio(0);
    }
    __builtin_amdgcn_sched_barrier(0);
  }

  lsum0 += __shfl_xor(lsum0, 16);
  lsum0 += __shfl_xor(lsum0, 32);
  lsum1 += __shfl_xor(lsum1, 16);
  lsum1 += __shfl_xor(lsum1, 32);
  if (lg == 0) {
    lsums[((sp * 8) + h) * MP + q0 + lc]      = lsum0;
    lsums[((sp * 8) + h) * MP + q0 + 16 + lc] = lsum1;
  }
#pragma unroll
  for (int g = 0; g < 2; ++g)
#pragma unroll
    for (int dt = 0; dt < 8; ++dt)
#pragma unroll
      for (int r = 0; r < 4; ++r) {
        int orow = q0 + g * 16 + lg * 4 + r;
        opart[(long)orow * EDIM + h * 128 + dt * 16 + lc] = f2b(oacc[g][dt][r]);
      }
}

// ---------------- combine partials: ob = (p0+p1+p2+p3)/(ls0+..+ls3) ---------
__global__ __launch_bounds__(256)
void k_comb(const short* __restrict__ p0, const short* __restrict__ p1,
            const short* __restrict__ p2, const short* __restrict__ p3,
            const float* __restrict__ ls, short* __restrict__ ob)
{
  int i = blockIdx.x * 256 + threadIdx.x;   // one 8-short group
  int q = i >> 7;
  int h = (i & 127) >> 4;
  float rinv = 1.f / (ls[h * MP + q] + ls[(8 + h) * MP + q] +
                      ls[(16 + h) * MP + q] + ls[(24 + h) * MP + q]);
  bf8 a = ((const bf8*)p0)[i];
  bf8 b = ((const bf8*)p1)[i];
  bf8 c = ((const bf8*)p2)[i];
  bf8 d = ((const bf8*)p3)[i];
  bf8 o;
#pragma unroll
  for (int j = 0; j < 8; ++j)
    o[j] = f2b((b2f(a[j]) + b2f(b[j]) + b2f(c[j]) + b2f(d[j])) * rinv);
  ((bf8*)ob)[i] = o;
}

// ---------------- launch ----------------
extern "C" void kernel_launch(void* const* d_in, const int* in_sizes, int n_in,
                              void* d_out, int out_size, void* d_ws, size_t ws_size,
                              hipStream_t stream)
{
  const float* x   = (const float*)d_in[0];
  const float* ipb = (const float*)d_in[20];
  const float* opb = (const float*)d_in[22];

  char* ws = (char*)d_ws;
  // regA [0, 25657344): xb -> aln -> {pt0, pt1, ob}
  // tail [23068672, 25657344): stats/bp/c1/cb2/lsums — written only AFTER
  // GEMM1 consumes xb (r11 lesson). pt2/pt3 live in dead w1b/w2b tails
  // (dead after GEMM1/GEMM2 respectively; attn runs after both).
  short*  xb     = (short*)(ws + 0);
  short*  aln    = (short*)(ws + 0);
  short*  pt0    = (short*)(ws + 0);
  short*  pt1    = (short*)(ws + 7602176);
  short*  ob     = (short*)(ws + 15466496);    // ends 23,068,672
  float2* stats  = (float2*)(ws + 23068672);   // 89,088 B
  float*  bp     = (float*)(ws + 23330816);    // 13,824 B
  float*  c1     = (float*)(ws + 23461888);    // 12,288 B
  float*  cb2    = (float*)(ws + 23592960);    // 12,288 B
  float*  lsums  = (float*)(ws + 23605248);    // 475,136 B, ends 24,080,384
  short*  h1     = (short*)(ws + 25657344);
  short*  proj   = (short*)(ws + 25657344);
  short*  w1b    = (short*)(ws + 48463872);
  short*  wprime = w1b;                        // W' = first 2 MB of w1b
  short*  pt2    = (short*)(ws + 55541760);    // dead w1b tail
  short*  pt3    = (short*)(ws + 63143936);    // tail of w1b + head of w2b (dead)
  short*  w2b    = (short*)(ws + 69697536);
  short*  wpb    = (short*)(ws + 75988992);
  short*  woT    = (short*)(ws + 82280448);
  short*  wtb    = (short*)(ws + 84377600);
  short*  vpT    = (short*)(ws + 91455488);

  // 1. merged conversions (x-pad, w1 x3, w2 x3, wt)
  CvtArgs ca;
  ca.s0 = x;                      ca.d0 = xb;
  ca.s1 = (const float*)d_in[1];  ca.d1 = w1b;
  ca.s2 = (const float*)d_in[7];  ca.d2 = w1b + 3538944;
  ca.s3 = (const float*)d_in[13]; ca.d3 = w1b + 7077888;
  ca.s4 = (const float*)d_in[3];  ca.d4 = w2b;
  ca.s5 = (const float*)d_in[9];  ca.d5 = w2b + 1048576;
  ca.s6 = (const float*)d_in[15]; ca.d6 = w2b + 2097152;
  ca.s7 = (const float*)d_in[23]; ca.d7 = wtb;
  k_cvtall<<<(SB7 + 255) / 256, 256, 0, stream>>>(ca);
  // 2. wpb with LN gamma folded
  k_cvtwp<<<3072, 256, 0, stream>>>((const float*)d_in[19], wpb,
      (const float*)d_in[5], (const float*)d_in[11], (const float*)d_in[17]);
  // 3. Wo^T
  dim3 gct(16, 16);
  k_cvt_t<<<gct, 256, 0, stream>>>((const float*)d_in[21], woT, 1024);

  dim3 g3(8, 29, 3);
  // 4. MLP first linear + GELU (consumes xb; regA/w1b tails dead after)
  k_gemm<GM_GELU><<<g3, 256, 0, stream>>>(xb, 0, w1b, 3538944,
      (const float*)d_in[2], (const float*)d_in[8], (const float*)d_in[14],
      h1, (long)MP * EDIM, EDIM, DIMV, nullptr);
  // 5. composite bias b' = opb @ Wt^T  (into now-dead xb tail)
  k_bvec<<<864, 256, 0, stream>>>((const float*)d_in[23], opb, bp);
  // 6. LN correction vectors c1, cb2 (into now-dead xb tail)
  dim3 gcv(256, 3);
  k_cvec<<<gcv, 256, 0, stream>>>((const float*)d_in[19],
      (const float*)d_in[5], (const float*)d_in[11], (const float*)d_in[17],
      (const float*)d_in[6], (const float*)d_in[12], (const float*)d_in[18],
      ipb, c1, cb2);
  // 7. W' = Wt @ Wo (into dead w1b slot head)
  dim3 gwp(8, 27, 1);
  k_gemm<GM_PLAIN><<<gwp, 256, 0, stream>>>(wtb, 0, woT, 0,
      nullptr, nullptr, nullptr, wprime, 0, EDIM, EDIM, nullptr);
  // 8. MLP second linear + bias (h1 -> aln; w2b dead after)
  k_gemm<GM_BIAS><<<g3, 256, 0, stream>>>(h1, (long)MP * EDIM, w2b, 1048576,
      (const float*)d_in[4], (const float*)d_in[10], (const float*)d_in[16],
      aln, (long)MP * EDIM, EDIM, EDIM, nullptr);
  // 9. per-row LN stats
  dim3 gst(MP / 4, 3);
  k_stats<<<gst, 256, 0, stream>>>(aln, stats);
  // 10. in_proj with fused LN (+q scale), aln -> proj
  k_gemmln<<<g3, 256, 0, stream>>>(aln, (long)MP * EDIM, wpb, 1048576,
      stats, c1, cb2, proj, (long)MP * EDIM);
  // 11. V transpose per head
  dim3 gt(MP / 64, 8);
  k_vtrans<<<gt, 256, 0, stream>>>(proj + 2L * MP * EDIM, vpT);
  // 12. attention, KV-split 4-way, single-buffered gld16 K/V (3 blocks/CU)
  k_attn<<<29 * 4 * 8, 256, 0, stream>>>(proj, proj + (long)MP * EDIM, vpT,
      pt0, pt1, pt2, pt3, lsums);
  // 13. combine partials
  k_comb<<<(MP * EDIM / 8) / 256, 256, 0, stream>>>(pt0, pt1, pt2, pt3, lsums, ob);
  // 14. composite (out_proj ∘ to_out): out = ob @ W'^T + b' + x (fp32 out)
  dim3 g5(27, 29, 1);
  k_gemm<GM_RESID><<<g5, 256, 0, stream>>>(ob, 0, wprime, 0,
      bp, bp, bp, d_out, 0, DIMV, EDIM, x);
}